// Round 5
// baseline (430.952 us; speedup 1.0000x reference)
//
#include <hip/hip_runtime.h>
#include <cstdint>
#include <cstddef>

typedef unsigned short u16;
typedef __bf16 bf16x8 __attribute__((ext_vector_type(8)));
typedef float f32x4 __attribute__((ext_vector_type(4)));

__device__ __forceinline__ float bf2f(u16 u) {
  unsigned int v = ((unsigned int)u) << 16;
  return __builtin_bit_cast(float, v);
}
__device__ __forceinline__ u16 f2bf(float f) {
  unsigned int v = __builtin_bit_cast(unsigned int, f);
  v += 0x7FFFu + ((v >> 16) & 1u);   // round-to-nearest-even
  return (u16)(v >> 16);
}

// async 16B global -> LDS (gfx950)
__device__ __forceinline__ void async16(u16* lds, const u16* g) {
  __builtin_amdgcn_global_load_lds(
      (const __attribute__((address_space(1))) unsigned int*)g,
      (__attribute__((address_space(3))) unsigned int*)lds, 16, 0, 0);
}

__device__ __forceinline__ void fma8(float* a, float d, uint4 p) {
  a[0] += d * bf2f((u16)p.x); a[1] += d * bf2f((u16)(p.x >> 16));
  a[2] += d * bf2f((u16)p.y); a[3] += d * bf2f((u16)(p.y >> 16));
  a[4] += d * bf2f((u16)p.z); a[5] += d * bf2f((u16)(p.z >> 16));
  a[6] += d * bf2f((u16)p.w); a[7] += d * bf2f((u16)(p.w >> 16));
}

// per-wave int64-vs-int32 edge dtype detection: checks high words of first 128
// entries (first 1KB, L2-hot). int64 random indices < 2^31 -> all high words 0.
__device__ __forceinline__ int wave_is64(const void* ep) {
  const unsigned* p = (const unsigned*)ep;
  const int lane = threadIdx.x & 63;
  unsigned v = p[2 * lane + 1] | p[2 * (lane + 64) + 1];
  unsigned long long bal = __ballot(v != 0u);
  return (bal == 0ull) ? 1 : 0;
}

__device__ __forceinline__ int edge_at(const void* ep, int is64, long long idx) {
  if (is64) return (int)((const long long*)ep)[idx];
  return ((const int*)ep)[idx];
}

// ---------------- diagnostics / fallback ----------------
__global__ void zero_f32(float* p, int n) {
  int i = blockIdx.x * 256 + threadIdx.x;
  if (i < n) p[i] = 0.f;
}

// ---------------- fused prep: cvt_pad + count_deg + 3x transpose_w ----------------
__global__ __launch_bounds__(256) void prep_fused(
    const float4* __restrict__ x, ushort4* __restrict__ xpad, int n_src4, int n_tot4,
    const void* __restrict__ ep, int* __restrict__ indeg, int E, int N,
    const float* __restrict__ W1, u16* __restrict__ wt1,
    const float* __restrict__ W2, u16* __restrict__ wt2,
    const float* __restrict__ W3, u16* __restrict__ wt3,
    int DIN, int DH, int DOUT,
    int nb_cvt, int nb_deg, int nb_w1, int nb_w2) {
  int b = blockIdx.x;
  if (b < nb_cvt) {                       // fp32 -> bf16 convert + pad
    int i = b * 256 + threadIdx.x;
    if (i < n_tot4) {
      ushort4 o = {0, 0, 0, 0};
      if (i < n_src4) {
        float4 v = x[i];
        o.x = f2bf(v.x); o.y = f2bf(v.y); o.z = f2bf(v.z); o.w = f2bf(v.w);
      }
      xpad[i] = o;
    }
    return;
  }
  b -= nb_cvt;
  if (b < nb_deg) {                       // in-degree count
    int is64 = wave_is64(ep);
    int e = b * 256 + threadIdx.x;
    if (e < E) {
      int d = edge_at(ep, is64, (long long)E + e);
      d = min(max(d, 0), N - 1);
      atomicAdd(&indeg[d], 1);
    }
    return;
  }
  b -= nb_deg;
  if (b < nb_w1) {                        // wt1[n*DIN+k] = W1[k*DH+n]
    int idx = b * 256 + threadIdx.x;
    if (idx < DIN * DH) {
      int n = idx / DIN, k = idx % DIN;
      wt1[idx] = f2bf(W1[k * DH + n]);
    }
    return;
  }
  b -= nb_w1;
  if (b < nb_w2) {                        // wt2[n*DH+k] = W2[k*DH+n]
    int idx = b * 256 + threadIdx.x;
    if (idx < DH * DH) {
      int n = idx / DH, k = idx % DH;
      wt2[idx] = f2bf(W2[k * DH + n]);
    }
    return;
  }
  b -= nb_w2;
  {                                       // wt3[n*DH+k] = W3[k*DOUT+n]
    int idx = b * 256 + threadIdx.x;
    if (idx < DH * DOUT) {
      int n = idx / DH, k = idx % DH;
      wt3[idx] = f2bf(W3[k * DOUT + n]);
    }
  }
}

// ---------------- single-block full scan: rp/fillc/dis from indeg ----------------
__global__ __launch_bounds__(1024) void scan_all(const int* __restrict__ indeg,
                                                 int* __restrict__ rp,
                                                 int* __restrict__ fillc,
                                                 float* __restrict__ dis,
                                                 int N, int E) {
  __shared__ int wsum[16];
  __shared__ int carry_s;
  const int t = threadIdx.x;
  const int lane = t & 63, w = t >> 6;    // 16 waves
  if (t == 0) carry_s = 0;
  __syncthreads();
  for (int base = 0; base < N; base += 1024) {
    const int i = base + t;
    const int v = (i < N) ? indeg[i] : 0;
    // wave-level inclusive scan
    int inc = v;
#pragma unroll
    for (int off = 1; off < 64; off <<= 1) {
      int u = __shfl_up(inc, off, 64);
      if (lane >= off) inc += u;
    }
    if (lane == 63) wsum[w] = inc;
    __syncthreads();
    if (w == 0) {                          // scan the 16 wave totals
      int s = (lane < 16) ? wsum[lane] : 0;
      int sinc = s;
#pragma unroll
      for (int off = 1; off < 16; off <<= 1) {
        int u = __shfl_up(sinc, off, 64);
        if (lane >= off) sinc += u;
      }
      if (lane < 16) wsum[lane] = sinc - s;   // exclusive wave prefix
    }
    __syncthreads();
    const int carry = carry_s;
    const int excl = carry + wsum[w] + inc - v;
    if (i < N) {
      rp[i] = excl;
      fillc[i] = excl;
      dis[i] = rsqrtf((float)(v + 1));    // +1 = self loop
    }
    __syncthreads();                       // all reads of carry_s done
    if (t == 1023) carry_s = carry + wsum[15] + inc;  // wave15 excl-prefix + its total
  }
  if (t == 0) rp[N] = E;
}

__global__ void fill_csr(const void* __restrict__ ep,
                         int* __restrict__ fill, int* __restrict__ col, int E, int N) {
  int is64 = wave_is64(ep);
  int e = blockIdx.x * 256 + threadIdx.x;
  if (e >= E) return;
  int s = edge_at(ep, is64, e);
  int d = edge_at(ep, is64, (long long)E + e);
  s = min(max(s, 0), N - 1);
  d = min(max(d, 0), N - 1);
  int pos = atomicAdd(&fill[d], 1);
  col[pos] = s;
}

// ---------------- GEMM: C[M,Nt] = A[M,256] @ Bt[Nt,256]^T, bf16 in/out, fp32 acc
// LDS in fragment order: chunk c=(blk16*4 + k8)*16 + row16, 16B each.
template <int BN>
__global__ __launch_bounds__(256) void gemm_bt(const u16* __restrict__ A,
                                               const u16* __restrict__ Bt,
                                               u16* __restrict__ C, int Nt) {
  constexpr int K = 256;
  constexpr int BK = 32;
  constexpr int ACH = (128 * BK) / 8;
  constexpr int BCH = (BN * BK) / 8;
  constexpr int WAVES_N = BN / 64;
  constexpr int WAVES_M = 4 / WAVES_N;
  constexpr int WMF = 128 / (WAVES_M * 16);
  constexpr int WNF = BN / (WAVES_N * 16);

  __shared__ __align__(16) u16 As[128 * BK];
  __shared__ __align__(16) u16 Bs[BN * BK];

  const int tid = threadIdx.x;
  const int bm = blockIdx.x, bn = blockIdx.y;
  const int wid = tid >> 6, lane = tid & 63;
  const int wm = wid % WAVES_M, wn = wid / WAVES_M;
  const int m0 = wm * (WMF * 16), n0 = wn * (WNF * 16);
  const int r16 = lane & 15, quad = lane >> 4;

  f32x4 acc[WMF][WNF];
  const f32x4 fzero = {0.f, 0.f, 0.f, 0.f};
#pragma unroll
  for (int i = 0; i < WMF; ++i)
#pragma unroll
    for (int j = 0; j < WNF; ++j) acc[i][j] = fzero;

  const u16* Ag = A + (size_t)bm * 128 * K;
  const u16* Bg = Bt + (size_t)bn * BN * K;

  for (int kb = 0; kb < K; kb += BK) {
    __syncthreads();
#pragma unroll
    for (int r = 0; r < ACH / 256; ++r) {
      int c = tid + r * 256;
      int rr = (c >> 6) * 16 + (c & 15);
      int ko = ((c >> 4) & 3) * 8;
      async16(&As[c * 8], Ag + (size_t)rr * K + kb + ko);
    }
#pragma unroll
    for (int r = 0; r < BCH / 256; ++r) {
      int c = tid + r * 256;
      int rr = (c >> 6) * 16 + (c & 15);
      int ko = ((c >> 4) & 3) * 8;
      async16(&Bs[c * 8], Bg + (size_t)rr * K + kb + ko);
    }
    __syncthreads();
    bf16x8 af[WMF], bfr[WNF];
#pragma unroll
    for (int i = 0; i < WMF; ++i)
      af[i] = *(const bf16x8*)(&As[((m0 >> 4) + i) * 512 + lane * 8]);
#pragma unroll
    for (int j = 0; j < WNF; ++j)
      bfr[j] = *(const bf16x8*)(&Bs[((n0 >> 4) + j) * 512 + lane * 8]);
#pragma unroll
    for (int i = 0; i < WMF; ++i)
#pragma unroll
      for (int j = 0; j < WNF; ++j)
        acc[i][j] = __builtin_amdgcn_mfma_f32_16x16x32_bf16(af[i], bfr[j], acc[i][j], 0, 0, 0);
  }
#pragma unroll
  for (int i = 0; i < WMF; ++i)
#pragma unroll
    for (int j = 0; j < WNF; ++j) {
      int gr = bm * 128 + m0 + i * 16 + quad * 4;   // C/D: col=lane&15, row=quad*4+r
      int gc = bn * BN + n0 + j * 16 + r16;
#pragma unroll
      for (int r = 0; r < 4; ++r)
        C[(size_t)(gr + r) * Nt + gc] = f2bf(acc[i][j][r]);
    }
}

// ---------------- aggregation, d=256: half-wave = 1 edge, 4 loads deep ----------------
__global__ __launch_bounds__(256) void agg_d256(const u16* __restrict__ h,
                                                const int* __restrict__ rp,
                                                const int* __restrict__ col,
                                                const float* __restrict__ dis,
                                                const float* __restrict__ bias,
                                                u16* __restrict__ out, int N) {
  const int wid = threadIdx.x >> 6, lane = threadIdx.x & 63;
  const int i = blockIdx.x * 4 + wid;
  if (i >= N) return;
  const int sub = lane >> 5;      // edge-pair selector
  const int l32 = lane & 31;
  const int c8 = l32 * 8;         // 8 features per lane
  const float di = dis[i];
  float a[8];
  {
    uint4 sv = *(const uint4*)(h + (size_t)i * 256 + c8);
    const float w = sub ? 0.f : di;     // self term once
    a[0] = w * bf2f((u16)sv.x); a[1] = w * bf2f((u16)(sv.x >> 16));
    a[2] = w * bf2f((u16)sv.y); a[3] = w * bf2f((u16)(sv.y >> 16));
    a[4] = w * bf2f((u16)sv.z); a[5] = w * bf2f((u16)(sv.z >> 16));
    a[6] = w * bf2f((u16)sv.w); a[7] = w * bf2f((u16)(sv.w >> 16));
  }
  const int e1 = rp[i + 1];
  for (int base = rp[i]; base < e1; base += 64) {
    int me = base + lane;
    int s_l = 0; float d_l = 0.f;
    if (me < e1) { s_l = col[me]; d_l = dis[s_l]; }
    const int cnt = min(64, e1 - base);
    const int cntR = (cnt + 7) & ~7;
    for (int t = 0; t < cntR; t += 8) {    // 8 edges/iter, 4 loads deep per lane
      int sA = __shfl(s_l, t + sub, 64);      float dA = __shfl(d_l, t + sub, 64);
      int sB = __shfl(s_l, t + 2 + sub, 64);  float dB = __shfl(d_l, t + 2 + sub, 64);
      int sC = __shfl(s_l, t + 4 + sub, 64);  float dC = __shfl(d_l, t + 4 + sub, 64);
      int sD = __shfl(s_l, t + 6 + sub, 64);  float dD = __shfl(d_l, t + 6 + sub, 64);
      uint4 pA = *(const uint4*)(h + (size_t)sA * 256 + c8);
      uint4 pB = *(const uint4*)(h + (size_t)sB * 256 + c8);
      uint4 pC = *(const uint4*)(h + (size_t)sC * 256 + c8);
      uint4 pD = *(const uint4*)(h + (size_t)sD * 256 + c8);
      fma8(a, dA, pA); fma8(a, dB, pB); fma8(a, dC, pC); fma8(a, dD, pD);
    }
  }
#pragma unroll
  for (int k = 0; k < 8; ++k) a[k] += __shfl_xor(a[k], 32, 64);
  if (sub == 0) {
    float4 b0 = *(const float4*)(bias + c8);
    float4 b1 = *(const float4*)(bias + c8 + 4);
    float r0 = fmaxf(di * a[0] + b0.x, 0.f), r1 = fmaxf(di * a[1] + b0.y, 0.f);
    float r2 = fmaxf(di * a[2] + b0.z, 0.f), r3 = fmaxf(di * a[3] + b0.w, 0.f);
    float r4 = fmaxf(di * a[4] + b1.x, 0.f), r5 = fmaxf(di * a[5] + b1.y, 0.f);
    float r6 = fmaxf(di * a[6] + b1.z, 0.f), r7 = fmaxf(di * a[7] + b1.w, 0.f);
    uint4 ov;
    ov.x = (unsigned)f2bf(r0) | ((unsigned)f2bf(r1) << 16);
    ov.y = (unsigned)f2bf(r2) | ((unsigned)f2bf(r3) << 16);
    ov.z = (unsigned)f2bf(r4) | ((unsigned)f2bf(r5) << 16);
    ov.w = (unsigned)f2bf(r6) | ((unsigned)f2bf(r7) << 16);
    *(uint4*)(out + (size_t)i * 256 + c8) = ov;
  }
}

// final layer: h bf16 [N,64], out fp32 [N,64]. 8-lane group = 1 edge, 2 loads deep.
__global__ __launch_bounds__(256) void agg_d64(const u16* __restrict__ h,
                                               const int* __restrict__ rp,
                                               const int* __restrict__ col,
                                               const float* __restrict__ dis,
                                               const float* __restrict__ bias,
                                               float* __restrict__ out, int N) {
  const int wid = threadIdx.x >> 6, lane = threadIdx.x & 63;
  const int i = blockIdx.x * 4 + wid;
  if (i >= N) return;
  const int grp = lane >> 3;      // edge slot 0..7
  const int l8 = lane & 7;
  const int c8 = l8 * 8;
  const float di = dis[i];
  float a[8];
  {
    uint4 sv = *(const uint4*)(h + (size_t)i * 64 + c8);
    const float w = (grp == 0) ? di : 0.f;
    a[0] = w * bf2f((u16)sv.x); a[1] = w * bf2f((u16)(sv.x >> 16));
    a[2] = w * bf2f((u16)sv.y); a[3] = w * bf2f((u16)(sv.y >> 16));
    a[4] = w * bf2f((u16)sv.z); a[5] = w * bf2f((u16)(sv.z >> 16));
    a[6] = w * bf2f((u16)sv.w); a[7] = w * bf2f((u16)(sv.w >> 16));
  }
  const int e1 = rp[i + 1];
  for (int base = rp[i]; base < e1; base += 64) {
    int me = base + lane;
    int s_l = 0; float d_l = 0.f;
    if (me < e1) { s_l = col[me]; d_l = dis[s_l]; }
    const int cnt = min(64, e1 - base);
    const int cntR = (cnt + 15) & ~15;
    for (int t = 0; t < cntR; t += 16) {
      int sA = __shfl(s_l, t + grp, 64);       float dA = __shfl(d_l, t + grp, 64);
      int sB = __shfl(s_l, t + 8 + grp, 64);   float dB = __shfl(d_l, t + 8 + grp, 64);
      uint4 pA = *(const uint4*)(h + (size_t)sA * 64 + c8);
      uint4 pB = *(const uint4*)(h + (size_t)sB * 64 + c8);
      fma8(a, dA, pA); fma8(a, dB, pB);
    }
  }
#pragma unroll
  for (int k = 0; k < 8; ++k) a[k] += __shfl_xor(a[k], 8, 64);
#pragma unroll
  for (int k = 0; k < 8; ++k) a[k] += __shfl_xor(a[k], 16, 64);
#pragma unroll
  for (int k = 0; k < 8; ++k) a[k] += __shfl_xor(a[k], 32, 64);
  if (lane < 8) {
    float4 b0 = *(const float4*)(bias + c8);
    float4 b1 = *(const float4*)(bias + c8 + 4);
    float4 o0, o1;
    o0.x = di * a[0] + b0.x; o0.y = di * a[1] + b0.y;
    o0.z = di * a[2] + b0.z; o0.w = di * a[3] + b0.w;
    o1.x = di * a[4] + b1.x; o1.y = di * a[5] + b1.y;
    o1.z = di * a[6] + b1.z; o1.w = di * a[7] + b1.w;
    *(float4*)(out + (size_t)i * 64 + c8) = o0;
    *(float4*)(out + (size_t)i * 64 + c8 + 4) = o1;
  }
}

// ---------------- launch ----------------
extern "C" void kernel_launch(void* const* d_in, const int* in_sizes, int n_in,
                              void* d_out, int out_size, void* d_ws, size_t ws_size,
                              hipStream_t stream) {
  if (n_in < 8) return;
  const float* x = (const float*)d_in[0];
  const void* eptr = d_in[1];
  const float* W1 = (const float*)d_in[2];
  const float* b1 = (const float*)d_in[3];
  const float* W2 = (const float*)d_in[4];
  const float* b2 = (const float*)d_in[5];
  const float* W3 = (const float*)d_in[6];
  const float* b3 = (const float*)d_in[7];
  float* out = (float*)d_out;

  const int DIN = 256, DH = 256;
  const int N = in_sizes[0] / DIN;       // 50000
  const int E = in_sizes[1] / 2;         // 800000
  const int DOUT = in_sizes[6] / DH;     // 64
  const int MT = (N + 127) / 128;        // 391
  const int Mpad = MT * 128;

  auto rnd = [](size_t b) { return (b + 255) & ~(size_t)255; };
  size_t required = 0;
  required += rnd((size_t)Mpad * DH * 2) * 2;
  required += rnd((size_t)E * 4);
  required += rnd((size_t)(N + 1) * 4);
  required += rnd((size_t)N * 4) * 3;
  required += rnd((size_t)DIN * DH * 2);
  required += rnd((size_t)DH * DH * 2);
  required += rnd((size_t)DH * DOUT * 2);
  if (ws_size < required) {
    zero_f32<<<(out_size + 255) / 256, 256, 0, stream>>>(out, out_size);
    return;
  }

  char* ws = (char*)d_ws;
  size_t off = 0;
  auto alloc = [&](size_t bytes) {
    char* p = ws + off;
    off = (off + bytes + 255) & ~(size_t)255;
    return p;
  };
  u16* xpad = (u16*)alloc((size_t)Mpad * DH * 2);
  u16* hbuf = (u16*)alloc((size_t)Mpad * DH * 2);
  int* colb = (int*)alloc((size_t)E * 4);
  int* rp = (int*)alloc((size_t)(N + 1) * 4);
  int* indeg = (int*)alloc((size_t)N * 4);
  int* fillc = (int*)alloc((size_t)N * 4);
  float* dis = (float*)alloc((size_t)N * 4);
  u16* wt1 = (u16*)alloc((size_t)DIN * DH * 2);
  u16* wt2 = (u16*)alloc((size_t)DH * DH * 2);
  u16* wt3 = (u16*)alloc((size_t)DH * DOUT * 2);

  hipMemsetAsync(indeg, 0, (size_t)N * 4, stream);

  const int n_tot4 = Mpad * DH / 4;
  const int nb_cvt = (n_tot4 + 255) / 256;
  const int nb_deg = (E + 255) / 256;
  const int nb_w1 = (DIN * DH + 255) / 256;
  const int nb_w2 = (DH * DH + 255) / 256;
  const int nb_w3 = (DH * DOUT + 255) / 256;
  prep_fused<<<nb_cvt + nb_deg + nb_w1 + nb_w2 + nb_w3, 256, 0, stream>>>(
      (const float4*)x, (ushort4*)xpad, N * DH / 4, n_tot4,
      eptr, indeg, E, N, W1, wt1, W2, wt2, W3, wt3,
      DIN, DH, DOUT, nb_cvt, nb_deg, nb_w1, nb_w2);

  scan_all<<<1, 1024, 0, stream>>>(indeg, rp, fillc, dis, N, E);
  fill_csr<<<(E + 255) / 256, 256, 0, stream>>>(eptr, fillc, colb, E, N);

  // layer 1
  gemm_bt<128><<<dim3(MT, DH / 128), 256, 0, stream>>>(xpad, wt1, hbuf, DH);
  agg_d256<<<(N + 3) / 4, 256, 0, stream>>>(hbuf, rp, colb, dis, b1, xpad, N);
  // layer 2
  gemm_bt<128><<<dim3(MT, DH / 128), 256, 0, stream>>>(xpad, wt2, hbuf, DH);
  agg_d256<<<(N + 3) / 4, 256, 0, stream>>>(hbuf, rp, colb, dis, b2, xpad, N);
  // layer 3
  gemm_bt<64><<<dim3(MT, DOUT / 64), 256, 0, stream>>>(xpad, wt3, hbuf, DOUT);
  agg_d64<<<(N + 3) / 4, 256, 0, stream>>>(hbuf, rp, colb, dis, b3, out, N);
}

// Round 6
// 415.433 us; speedup vs baseline: 1.0374x; 1.0374x over previous
//
#include <hip/hip_runtime.h>
#include <cstdint>
#include <cstddef>

typedef unsigned short u16;
typedef __bf16 bf16x8 __attribute__((ext_vector_type(8)));
typedef float f32x4 __attribute__((ext_vector_type(4)));

__device__ __forceinline__ float bf2f(u16 u) {
  unsigned int v = ((unsigned int)u) << 16;
  return __builtin_bit_cast(float, v);
}
__device__ __forceinline__ u16 f2bf(float f) {
  unsigned int v = __builtin_bit_cast(unsigned int, f);
  v += 0x7FFFu + ((v >> 16) & 1u);   // round-to-nearest-even
  return (u16)(v >> 16);
}

__device__ __forceinline__ void fma8(float* a, float d, uint4 p) {
  a[0] += d * bf2f((u16)p.x); a[1] += d * bf2f((u16)(p.x >> 16));
  a[2] += d * bf2f((u16)p.y); a[3] += d * bf2f((u16)(p.y >> 16));
  a[4] += d * bf2f((u16)p.z); a[5] += d * bf2f((u16)(p.z >> 16));
  a[6] += d * bf2f((u16)p.w); a[7] += d * bf2f((u16)(p.w >> 16));
}

// per-wave int64-vs-int32 edge dtype detection (first 1KB, L2-hot)
__device__ __forceinline__ int wave_is64(const void* ep) {
  const unsigned* p = (const unsigned*)ep;
  const int lane = threadIdx.x & 63;
  unsigned v = p[2 * lane + 1] | p[2 * (lane + 64) + 1];
  unsigned long long bal = __ballot(v != 0u);
  return (bal == 0ull) ? 1 : 0;
}

__device__ __forceinline__ int edge_at(const void* ep, int is64, long long idx) {
  if (is64) return (int)((const long long*)ep)[idx];
  return ((const int*)ep)[idx];
}

// ---------------- diagnostics / fallback ----------------
__global__ void zero_f32(float* p, int n) {
  int i = blockIdx.x * 256 + threadIdx.x;
  if (i < n) p[i] = 0.f;
}

// ---------------- fused prep: cvt_pad + count_deg + 3x transpose_w ----------------
__global__ __launch_bounds__(256) void prep_fused(
    const float4* __restrict__ x, ushort4* __restrict__ xpad, int n_src4, int n_tot4,
    const void* __restrict__ ep, int* __restrict__ indeg, int E, int N,
    const float* __restrict__ W1, u16* __restrict__ wt1,
    const float* __restrict__ W2, u16* __restrict__ wt2,
    const float* __restrict__ W3, u16* __restrict__ wt3,
    int DIN, int DH, int DOUT,
    int nb_cvt, int nb_deg, int nb_w1, int nb_w2) {
  int b = blockIdx.x;
  if (b < nb_cvt) {                       // fp32 -> bf16 convert + pad
    int i = b * 256 + threadIdx.x;
    if (i < n_tot4) {
      ushort4 o = {0, 0, 0, 0};
      if (i < n_src4) {
        float4 v = x[i];
        o.x = f2bf(v.x); o.y = f2bf(v.y); o.z = f2bf(v.z); o.w = f2bf(v.w);
      }
      xpad[i] = o;
    }
    return;
  }
  b -= nb_cvt;
  if (b < nb_deg) {                       // in-degree count
    int is64 = wave_is64(ep);
    int e = b * 256 + threadIdx.x;
    if (e < E) {
      int d = edge_at(ep, is64, (long long)E + e);
      d = min(max(d, 0), N - 1);
      atomicAdd(&indeg[d], 1);
    }
    return;
  }
  b -= nb_deg;
  if (b < nb_w1) {                        // wt1[n*DIN+k] = W1[k*DH+n]
    int idx = b * 256 + threadIdx.x;
    if (idx < DIN * DH) {
      int n = idx / DIN, k = idx % DIN;
      wt1[idx] = f2bf(W1[k * DH + n]);
    }
    return;
  }
  b -= nb_w1;
  if (b < nb_w2) {                        // wt2[n*DH+k] = W2[k*DH+n]
    int idx = b * 256 + threadIdx.x;
    if (idx < DH * DH) {
      int n = idx / DH, k = idx % DH;
      wt2[idx] = f2bf(W2[k * DH + n]);
    }
    return;
  }
  b -= nb_w2;
  {                                       // wt3[n*DH+k] = W3[k*DOUT+n]
    int idx = b * 256 + threadIdx.x;
    if (idx < DH * DOUT) {
      int n = idx / DH, k = idx % DH;
      wt3[idx] = f2bf(W3[k * DOUT + n]);
    }
  }
}

// ---------------- parallel CSR scan chain (R4 structure) ----------------
__global__ void scan_block(const int* __restrict__ indeg, int* __restrict__ rp,
                           int* __restrict__ bsums, int N) {
  __shared__ int tmp[1024];
  const int t = threadIdx.x;
  const int i = blockIdx.x * 1024 + t;
  int v = (i < N) ? indeg[i] : 0;
  tmp[t] = v;
  __syncthreads();
  for (int off = 1; off < 1024; off <<= 1) {
    int add = (t >= off) ? tmp[t - off] : 0;
    __syncthreads();
    tmp[t] += add;
    __syncthreads();
  }
  if (i < N) rp[i] = tmp[t] - v;          // exclusive
  if (t == 0) bsums[blockIdx.x] = tmp[1023];
}

__global__ void scan_tops_wave(int* bsums, int nb) {
  const int lane = threadIdx.x & 63;
  int v = (lane < nb) ? bsums[lane] : 0;
  int inc = v;
  for (int off = 1; off < 64; off <<= 1) {
    int u = __shfl_up(inc, off, 64);
    if (lane >= off) inc += u;
  }
  if (lane < nb) bsums[lane] = inc - v;
}

__global__ void scan_tops_serial(int* bsums, int nb) {
  if (threadIdx.x == 0 && blockIdx.x == 0) {
    int run = 0;
    for (int b = 0; b < nb; ++b) { int v = bsums[b]; bsums[b] = run; run += v; }
  }
}

__global__ void scan_fix(int* __restrict__ rp, const int* __restrict__ bsums,
                         const int* __restrict__ indeg, int* __restrict__ fill,
                         float* __restrict__ dis, int N, int E) {
  const int i = blockIdx.x * 256 + threadIdx.x;
  if (i == 0) rp[N] = E;
  if (i >= N) return;
  int r = rp[i] + bsums[i >> 10];
  rp[i] = r;
  fill[i] = r;
  dis[i] = rsqrtf((float)(indeg[i] + 1));  // +1 = self loop
}

__global__ void fill_csr(const void* __restrict__ ep,
                         int* __restrict__ fill, int* __restrict__ col, int E, int N) {
  int is64 = wave_is64(ep);
  int e = blockIdx.x * 256 + threadIdx.x;
  if (e >= E) return;
  int s = edge_at(ep, is64, e);
  int d = edge_at(ep, is64, (long long)E + e);
  s = min(max(s, 0), N - 1);
  d = min(max(d, 0), N - 1);
  int pos = atomicAdd(&fill[d], 1);
  col[pos] = s;
}

// ---------------- direct (LDS-free) GEMM: C[M,Nt] = A[M,256] @ Bt[Nt,256]^T
// A,Bt bf16 row-major with K=256 contiguous. Each wave loads its MFMA fragments
// straight from global (16B per lane, row-slice = A[m=lane&15][k=quad*8+j]).
// No barriers -> compiler pipelines loads across MFMAs. A/B are L1/L2-resident.
template <int BN>
__global__ __launch_bounds__(256) void gemm_direct(const u16* __restrict__ A,
                                                   const u16* __restrict__ Bt,
                                                   u16* __restrict__ C, int Nt) {
  constexpr int K = 256;
  constexpr int WAVES_N = BN / 64;         // 2 (BN=128) or 1 (BN=64)
  constexpr int WAVES_M = 4 / WAVES_N;
  constexpr int WMF = 128 / (WAVES_M * 16);
  constexpr int WNF = BN / (WAVES_N * 16);

  const int tid = threadIdx.x;
  const int bm = blockIdx.x, bn = blockIdx.y;
  const int wid = tid >> 6, lane = tid & 63;
  const int wm = wid % WAVES_M, wn = wid / WAVES_M;
  const int m0 = wm * (WMF * 16), n0 = wn * (WNF * 16);
  const int r16 = lane & 15, quad = lane >> 4;

  f32x4 acc[WMF][WNF];
  const f32x4 fzero = {0.f, 0.f, 0.f, 0.f};
#pragma unroll
  for (int i = 0; i < WMF; ++i)
#pragma unroll
    for (int j = 0; j < WNF; ++j) acc[i][j] = fzero;

  const u16* Ap[WMF];
  const u16* Bp[WNF];
#pragma unroll
  for (int i = 0; i < WMF; ++i)
    Ap[i] = A + (size_t)(bm * 128 + m0 + i * 16 + r16) * K + quad * 8;
#pragma unroll
  for (int j = 0; j < WNF; ++j)
    Bp[j] = Bt + (size_t)(bn * BN + n0 + j * 16 + r16) * K + quad * 8;

#pragma unroll
  for (int kb = 0; kb < K; kb += 32) {
    bf16x8 af[WMF], bfr[WNF];
#pragma unroll
    for (int i = 0; i < WMF; ++i) af[i] = *(const bf16x8*)(Ap[i] + kb);
#pragma unroll
    for (int j = 0; j < WNF; ++j) bfr[j] = *(const bf16x8*)(Bp[j] + kb);
#pragma unroll
    for (int i = 0; i < WMF; ++i)
#pragma unroll
      for (int j = 0; j < WNF; ++j)
        acc[i][j] = __builtin_amdgcn_mfma_f32_16x16x32_bf16(af[i], bfr[j], acc[i][j], 0, 0, 0);
  }
#pragma unroll
  for (int i = 0; i < WMF; ++i)
#pragma unroll
    for (int j = 0; j < WNF; ++j) {
      int gr = bm * 128 + m0 + i * 16 + quad * 4;   // C/D: col=lane&15, row=quad*4+r
      int gc = bn * BN + n0 + j * 16 + r16;
#pragma unroll
      for (int r = 0; r < 4; ++r)
        C[(size_t)(gr + r) * Nt + gc] = f2bf(acc[i][j][r]);
    }
}

// ---------------- aggregation, d=256: half-wave = 1 edge, 4 loads deep ----------------
__global__ __launch_bounds__(256) void agg_d256(const u16* __restrict__ h,
                                                const int* __restrict__ rp,
                                                const int* __restrict__ col,
                                                const float* __restrict__ dis,
                                                const float* __restrict__ bias,
                                                u16* __restrict__ out, int N) {
  const int wid = threadIdx.x >> 6, lane = threadIdx.x & 63;
  const int i = blockIdx.x * 4 + wid;
  if (i >= N) return;
  const int sub = lane >> 5;      // edge-pair selector
  const int l32 = lane & 31;
  const int c8 = l32 * 8;         // 8 features per lane
  const float di = dis[i];
  float a[8];
  {
    uint4 sv = *(const uint4*)(h + (size_t)i * 256 + c8);
    const float w = sub ? 0.f : di;     // self term once
    a[0] = w * bf2f((u16)sv.x); a[1] = w * bf2f((u16)(sv.x >> 16));
    a[2] = w * bf2f((u16)sv.y); a[3] = w * bf2f((u16)(sv.y >> 16));
    a[4] = w * bf2f((u16)sv.z); a[5] = w * bf2f((u16)(sv.z >> 16));
    a[6] = w * bf2f((u16)sv.w); a[7] = w * bf2f((u16)(sv.w >> 16));
  }
  const int e1 = rp[i + 1];
  for (int base = rp[i]; base < e1; base += 64) {
    int me = base + lane;
    int s_l = 0; float d_l = 0.f;
    if (me < e1) { s_l = col[me]; d_l = dis[s_l]; }
    const int cnt = min(64, e1 - base);
    const int cntR = (cnt + 7) & ~7;
    for (int t = 0; t < cntR; t += 8) {    // 8 edges/iter, 4 loads deep per lane
      int sA = __shfl(s_l, t + sub, 64);      float dA = __shfl(d_l, t + sub, 64);
      int sB = __shfl(s_l, t + 2 + sub, 64);  float dB = __shfl(d_l, t + 2 + sub, 64);
      int sC = __shfl(s_l, t + 4 + sub, 64);  float dC = __shfl(d_l, t + 4 + sub, 64);
      int sD = __shfl(s_l, t + 6 + sub, 64);  float dD = __shfl(d_l, t + 6 + sub, 64);
      uint4 pA = *(const uint4*)(h + (size_t)sA * 256 + c8);
      uint4 pB = *(const uint4*)(h + (size_t)sB * 256 + c8);
      uint4 pC = *(const uint4*)(h + (size_t)sC * 256 + c8);
      uint4 pD = *(const uint4*)(h + (size_t)sD * 256 + c8);
      fma8(a, dA, pA); fma8(a, dB, pB); fma8(a, dC, pC); fma8(a, dD, pD);
    }
  }
#pragma unroll
  for (int k = 0; k < 8; ++k) a[k] += __shfl_xor(a[k], 32, 64);
  if (sub == 0) {
    float4 b0 = *(const float4*)(bias + c8);
    float4 b1 = *(const float4*)(bias + c8 + 4);
    float r0 = fmaxf(di * a[0] + b0.x, 0.f), r1 = fmaxf(di * a[1] + b0.y, 0.f);
    float r2 = fmaxf(di * a[2] + b0.z, 0.f), r3 = fmaxf(di * a[3] + b0.w, 0.f);
    float r4 = fmaxf(di * a[4] + b1.x, 0.f), r5 = fmaxf(di * a[5] + b1.y, 0.f);
    float r6 = fmaxf(di * a[6] + b1.z, 0.f), r7 = fmaxf(di * a[7] + b1.w, 0.f);
    uint4 ov;
    ov.x = (unsigned)f2bf(r0) | ((unsigned)f2bf(r1) << 16);
    ov.y = (unsigned)f2bf(r2) | ((unsigned)f2bf(r3) << 16);
    ov.z = (unsigned)f2bf(r4) | ((unsigned)f2bf(r5) << 16);
    ov.w = (unsigned)f2bf(r6) | ((unsigned)f2bf(r7) << 16);
    *(uint4*)(out + (size_t)i * 256 + c8) = ov;
  }
}

// final layer: h bf16 [N,64], out fp32 [N,64]. 8-lane group = 1 edge, 2 loads deep.
__global__ __launch_bounds__(256) void agg_d64(const u16* __restrict__ h,
                                               const int* __restrict__ rp,
                                               const int* __restrict__ col,
                                               const float* __restrict__ dis,
                                               const float* __restrict__ bias,
                                               float* __restrict__ out, int N) {
  const int wid = threadIdx.x >> 6, lane = threadIdx.x & 63;
  const int i = blockIdx.x * 4 + wid;
  if (i >= N) return;
  const int grp = lane >> 3;      // edge slot 0..7
  const int l8 = lane & 7;
  const int c8 = l8 * 8;
  const float di = dis[i];
  float a[8];
  {
    uint4 sv = *(const uint4*)(h + (size_t)i * 64 + c8);
    const float w = (grp == 0) ? di : 0.f;
    a[0] = w * bf2f((u16)sv.x); a[1] = w * bf2f((u16)(sv.x >> 16));
    a[2] = w * bf2f((u16)sv.y); a[3] = w * bf2f((u16)(sv.y >> 16));
    a[4] = w * bf2f((u16)sv.z); a[5] = w * bf2f((u16)(sv.z >> 16));
    a[6] = w * bf2f((u16)sv.w); a[7] = w * bf2f((u16)(sv.w >> 16));
  }
  const int e1 = rp[i + 1];
  for (int base = rp[i]; base < e1; base += 64) {
    int me = base + lane;
    int s_l = 0; float d_l = 0.f;
    if (me < e1) { s_l = col[me]; d_l = dis[s_l]; }
    const int cnt = min(64, e1 - base);
    const int cntR = (cnt + 15) & ~15;
    for (int t = 0; t < cntR; t += 16) {
      int sA = __shfl(s_l, t + grp, 64);       float dA = __shfl(d_l, t + grp, 64);
      int sB = __shfl(s_l, t + 8 + grp, 64);   float dB = __shfl(d_l, t + 8 + grp, 64);
      uint4 pA = *(const uint4*)(h + (size_t)sA * 64 + c8);
      uint4 pB = *(const uint4*)(h + (size_t)sB * 64 + c8);
      fma8(a, dA, pA); fma8(a, dB, pB);
    }
  }
#pragma unroll
  for (int k = 0; k < 8; ++k) a[k] += __shfl_xor(a[k], 8, 64);
#pragma unroll
  for (int k = 0; k < 8; ++k) a[k] += __shfl_xor(a[k], 16, 64);
#pragma unroll
  for (int k = 0; k < 8; ++k) a[k] += __shfl_xor(a[k], 32, 64);
  if (lane < 8) {
    float4 b0 = *(const float4*)(bias + c8);
    float4 b1 = *(const float4*)(bias + c8 + 4);
    float4 o0, o1;
    o0.x = di * a[0] + b0.x; o0.y = di * a[1] + b0.y;
    o0.z = di * a[2] + b0.z; o0.w = di * a[3] + b0.w;
    o1.x = di * a[4] + b1.x; o1.y = di * a[5] + b1.y;
    o1.z = di * a[6] + b1.z; o1.w = di * a[7] + b1.w;
    *(float4*)(out + (size_t)i * 64 + c8) = o0;
    *(float4*)(out + (size_t)i * 64 + c8 + 4) = o1;
  }
}

// ---------------- launch ----------------
extern "C" void kernel_launch(void* const* d_in, const int* in_sizes, int n_in,
                              void* d_out, int out_size, void* d_ws, size_t ws_size,
                              hipStream_t stream) {
  if (n_in < 8) return;
  const float* x = (const float*)d_in[0];
  const void* eptr = d_in[1];
  const float* W1 = (const float*)d_in[2];
  const float* b1 = (const float*)d_in[3];
  const float* W2 = (const float*)d_in[4];
  const float* b2 = (const float*)d_in[5];
  const float* W3 = (const float*)d_in[6];
  const float* b3 = (const float*)d_in[7];
  float* out = (float*)d_out;

  const int DIN = 256, DH = 256;
  const int N = in_sizes[0] / DIN;       // 50000
  const int E = in_sizes[1] / 2;         // 800000
  const int DOUT = in_sizes[6] / DH;     // 64
  const int MT = (N + 127) / 128;        // 391
  const int Mpad = MT * 128;

  auto rnd = [](size_t b) { return (b + 255) & ~(size_t)255; };
  size_t required = 0;
  required += rnd((size_t)Mpad * DH * 2) * 2;
  required += rnd((size_t)E * 4);
  required += rnd((size_t)(N + 1) * 4);
  required += rnd((size_t)N * 4) * 3;
  required += rnd((size_t)DIN * DH * 2);
  required += rnd((size_t)DH * DH * 2);
  required += rnd((size_t)DH * DOUT * 2);
  required += 512;
  if (ws_size < required) {
    zero_f32<<<(out_size + 255) / 256, 256, 0, stream>>>(out, out_size);
    return;
  }

  char* ws = (char*)d_ws;
  size_t off = 0;
  auto alloc = [&](size_t bytes) {
    char* p = ws + off;
    off = (off + bytes + 255) & ~(size_t)255;
    return p;
  };
  u16* xpad = (u16*)alloc((size_t)Mpad * DH * 2);
  u16* hbuf = (u16*)alloc((size_t)Mpad * DH * 2);
  int* colb = (int*)alloc((size_t)E * 4);
  int* rp = (int*)alloc((size_t)(N + 1) * 4);
  int* indeg = (int*)alloc((size_t)N * 4);
  int* fillc = (int*)alloc((size_t)N * 4);
  float* dis = (float*)alloc((size_t)N * 4);
  u16* wt1 = (u16*)alloc((size_t)DIN * DH * 2);
  u16* wt2 = (u16*)alloc((size_t)DH * DH * 2);
  u16* wt3 = (u16*)alloc((size_t)DH * DOUT * 2);
  int* bsums = (int*)alloc(64 * 4);

  hipMemsetAsync(indeg, 0, (size_t)N * 4, stream);

  const int n_tot4 = Mpad * DH / 4;
  const int nb_cvt = (n_tot4 + 255) / 256;
  const int nb_deg = (E + 255) / 256;
  const int nb_w1 = (DIN * DH + 255) / 256;
  const int nb_w2 = (DH * DH + 255) / 256;
  const int nb_w3 = (DH * DOUT + 255) / 256;
  prep_fused<<<nb_cvt + nb_deg + nb_w1 + nb_w2 + nb_w3, 256, 0, stream>>>(
      (const float4*)x, (ushort4*)xpad, N * DH / 4, n_tot4,
      eptr, indeg, E, N, W1, wt1, W2, wt2, W3, wt3,
      DIN, DH, DOUT, nb_cvt, nb_deg, nb_w1, nb_w2);

  const int nsb = (N + 1023) / 1024;
  scan_block<<<nsb, 1024, 0, stream>>>(indeg, rp, bsums, N);
  if (nsb <= 64)
    scan_tops_wave<<<1, 64, 0, stream>>>(bsums, nsb);
  else
    scan_tops_serial<<<1, 64, 0, stream>>>(bsums, nsb);
  scan_fix<<<(N + 255) / 256, 256, 0, stream>>>(rp, bsums, indeg, fillc, dis, N, E);
  fill_csr<<<(E + 255) / 256, 256, 0, stream>>>(eptr, fillc, colb, E, N);

  // layer 1
  gemm_direct<128><<<dim3(MT, DH / 128), 256, 0, stream>>>(xpad, wt1, hbuf, DH);
  agg_d256<<<(N + 3) / 4, 256, 0, stream>>>(hbuf, rp, colb, dis, b1, xpad, N);
  // layer 2
  gemm_direct<128><<<dim3(MT, DH / 128), 256, 0, stream>>>(xpad, wt2, hbuf, DH);
  agg_d256<<<(N + 3) / 4, 256, 0, stream>>>(hbuf, rp, colb, dis, b2, xpad, N);
  // layer 3
  gemm_direct<64><<<dim3(MT, DOUT / 64), 256, 0, stream>>>(xpad, wt3, hbuf, DOUT);
  agg_d64<<<(N + 3) / 4, 256, 0, stream>>>(hbuf, rp, colb, dis, b3, out, N);
}

// Round 7
// 392.259 us; speedup vs baseline: 1.0986x; 1.0591x over previous
//
#include <hip/hip_runtime.h>
#include <cstdint>
#include <cstddef>

typedef unsigned short u16;
typedef __bf16 bf16x8 __attribute__((ext_vector_type(8)));
typedef float f32x4 __attribute__((ext_vector_type(4)));

__device__ __forceinline__ float bf2f(u16 u) {
  unsigned int v = ((unsigned int)u) << 16;
  return __builtin_bit_cast(float, v);
}
__device__ __forceinline__ u16 f2bf(float f) {
  unsigned int v = __builtin_bit_cast(unsigned int, f);
  v += 0x7FFFu + ((v >> 16) & 1u);   // round-to-nearest-even
  return (u16)(v >> 16);
}

// async 16B global -> LDS (gfx950)
__device__ __forceinline__ void async16(u16* lds, const u16* g) {
  __builtin_amdgcn_global_load_lds(
      (const __attribute__((address_space(1))) unsigned int*)g,
      (__attribute__((address_space(3))) unsigned int*)lds, 16, 0, 0);
}

__device__ __forceinline__ void fma8(float* a, float d, uint4 p) {
  a[0] += d * bf2f((u16)p.x); a[1] += d * bf2f((u16)(p.x >> 16));
  a[2] += d * bf2f((u16)p.y); a[3] += d * bf2f((u16)(p.y >> 16));
  a[4] += d * bf2f((u16)p.z); a[5] += d * bf2f((u16)(p.z >> 16));
  a[6] += d * bf2f((u16)p.w); a[7] += d * bf2f((u16)(p.w >> 16));
}

// per-wave int64-vs-int32 edge dtype detection (first 1KB, L2-hot)
__device__ __forceinline__ int wave_is64(const void* ep) {
  const unsigned* p = (const unsigned*)ep;
  const int lane = threadIdx.x & 63;
  unsigned v = p[2 * lane + 1] | p[2 * (lane + 64) + 1];
  unsigned long long bal = __ballot(v != 0u);
  return (bal == 0ull) ? 1 : 0;
}

__device__ __forceinline__ int edge_at(const void* ep, int is64, long long idx) {
  if (is64) return (int)((const long long*)ep)[idx];
  return ((const int*)ep)[idx];
}

// ---------------- diagnostics / fallback ----------------
__global__ void zero_f32(float* p, int n) {
  int i = blockIdx.x * 256 + threadIdx.x;
  if (i < n) p[i] = 0.f;
}

// ---------------- fused prep: cvt_pad + count_deg + 3x transpose_w ----------------
__global__ __launch_bounds__(256) void prep_fused(
    const float4* __restrict__ x, ushort4* __restrict__ xpad, int n_src4, int n_tot4,
    const void* __restrict__ ep, int* __restrict__ indeg, int E, int N,
    const float* __restrict__ W1, u16* __restrict__ wt1,
    const float* __restrict__ W2, u16* __restrict__ wt2,
    const float* __restrict__ W3, u16* __restrict__ wt3,
    int DIN, int DH, int DOUT,
    int nb_cvt, int nb_deg, int nb_w1, int nb_w2) {
  int b = blockIdx.x;
  if (b < nb_cvt) {                       // fp32 -> bf16 convert + pad
    int i = b * 256 + threadIdx.x;
    if (i < n_tot4) {
      ushort4 o = {0, 0, 0, 0};
      if (i < n_src4) {
        float4 v = x[i];
        o.x = f2bf(v.x); o.y = f2bf(v.y); o.z = f2bf(v.z); o.w = f2bf(v.w);
      }
      xpad[i] = o;
    }
    return;
  }
  b -= nb_cvt;
  if (b < nb_deg) {                       // in-degree count
    int is64 = wave_is64(ep);
    int e = b * 256 + threadIdx.x;
    if (e < E) {
      int d = edge_at(ep, is64, (long long)E + e);
      d = min(max(d, 0), N - 1);
      atomicAdd(&indeg[d], 1);
    }
    return;
  }
  b -= nb_deg;
  if (b < nb_w1) {                        // wt1[n*DIN+k] = W1[k*DH+n]
    int idx = b * 256 + threadIdx.x;
    if (idx < DIN * DH) {
      int n = idx / DIN, k = idx % DIN;
      wt1[idx] = f2bf(W1[k * DH + n]);
    }
    return;
  }
  b -= nb_w1;
  if (b < nb_w2) {                        // wt2[n*DH+k] = W2[k*DH+n]
    int idx = b * 256 + threadIdx.x;
    if (idx < DH * DH) {
      int n = idx / DH, k = idx % DH;
      wt2[idx] = f2bf(W2[k * DH + n]);
    }
    return;
  }
  b -= nb_w2;
  {                                       // wt3[n*DH+k] = W3[k*DOUT+n]
    int idx = b * 256 + threadIdx.x;
    if (idx < DH * DOUT) {
      int n = idx / DH, k = idx % DH;
      wt3[idx] = f2bf(W3[k * DOUT + n]);
    }
  }
}

// ---------------- parallel CSR scan chain ----------------
__global__ void scan_block(const int* __restrict__ indeg, int* __restrict__ rp,
                           int* __restrict__ bsums, int N) {
  __shared__ int tmp[1024];
  const int t = threadIdx.x;
  const int i = blockIdx.x * 1024 + t;
  int v = (i < N) ? indeg[i] : 0;
  tmp[t] = v;
  __syncthreads();
  for (int off = 1; off < 1024; off <<= 1) {
    int add = (t >= off) ? tmp[t - off] : 0;
    __syncthreads();
    tmp[t] += add;
    __syncthreads();
  }
  if (i < N) rp[i] = tmp[t] - v;          // exclusive
  if (t == 0) bsums[blockIdx.x] = tmp[1023];
}

__global__ void scan_tops_wave(int* bsums, int nb) {
  const int lane = threadIdx.x & 63;
  int v = (lane < nb) ? bsums[lane] : 0;
  int inc = v;
  for (int off = 1; off < 64; off <<= 1) {
    int u = __shfl_up(inc, off, 64);
    if (lane >= off) inc += u;
  }
  if (lane < nb) bsums[lane] = inc - v;
}

__global__ void scan_tops_serial(int* bsums, int nb) {
  if (threadIdx.x == 0 && blockIdx.x == 0) {
    int run = 0;
    for (int b = 0; b < nb; ++b) { int v = bsums[b]; bsums[b] = run; run += v; }
  }
}

__global__ void scan_fix(int* __restrict__ rp, const int* __restrict__ bsums,
                         const int* __restrict__ indeg,
                         float* __restrict__ dis, int N, int E) {
  const int i = blockIdx.x * 256 + threadIdx.x;
  if (i == 0) rp[N] = E;
  if (i >= N) return;
  int r = rp[i] + bsums[i >> 10];
  rp[i] = r;
  dis[i] = rsqrtf((float)(indeg[i] + 1));  // +1 = self loop
}

// ---------------- bucketed CSR build (coalesced writes; needs N <= 65536) -----
// bucket b = dst >> 8 (256 nodes each). NCHUNK edge chunks.
#define NCHUNK 64

// A: per-chunk histogram over buckets. cnt[b*NCHUNK + c]
__global__ __launch_bounds__(256) void csr_hist(const void* __restrict__ ep,
                                                int* __restrict__ cnt, int E, int N) {
  __shared__ int h[256];
  h[threadIdx.x] = 0;
  __syncthreads();
  int is64 = wave_is64(ep);
  const int chunk = blockIdx.x;
  const int per = (E + NCHUNK - 1) / NCHUNK;
  const int e0 = chunk * per, e1 = min(e0 + per, E);
  for (int e = e0 + threadIdx.x; e < e1; e += 256) {
    int d = edge_at(ep, is64, (long long)E + e);
    d = min(max(d, 0), N - 1);
    atomicAdd(&h[d >> 8], 1);
  }
  __syncthreads();
  cnt[threadIdx.x * NCHUNK + chunk] = h[threadIdx.x];
}

// B: per-bucket exclusive scan of chunk counts; base = rp[b*256]
__global__ void csr_scan2(const int* __restrict__ cnt, const int* __restrict__ rp,
                          int* __restrict__ off, int N) {
  const int b = blockIdx.x;                // bucket
  const int lane = threadIdx.x & 63;       // NCHUNK == 64 threads
  int v = cnt[b * NCHUNK + lane];
  int inc = v;
#pragma unroll
  for (int o = 1; o < 64; o <<= 1) {
    int u = __shfl_up(inc, o, 64);
    if (lane >= o) inc += u;
  }
  const int base = rp[min(b * 256, N)];
  off[b * NCHUNK + lane] = base + inc - v;
}

// C: chunked scatter into bucket-contiguous tmp (packed dst16|src16)
__global__ __launch_bounds__(256) void csr_bucket(const void* __restrict__ ep,
                                                  const int* __restrict__ off,
                                                  unsigned* __restrict__ tmp,
                                                  int E, int N) {
  __shared__ int cur[256];
  const int chunk = blockIdx.x;
  const int nbuck = (N + 255) >> 8;
  if ((int)threadIdx.x < nbuck) cur[threadIdx.x] = off[threadIdx.x * NCHUNK + chunk];
  __syncthreads();
  int is64 = wave_is64(ep);
  const int per = (E + NCHUNK - 1) / NCHUNK;
  const int e0 = chunk * per, e1 = min(e0 + per, E);
  for (int e = e0 + threadIdx.x; e < e1; e += 256) {
    int s = edge_at(ep, is64, e);
    int d = edge_at(ep, is64, (long long)E + e);
    s = min(max(s, 0), N - 1);
    d = min(max(d, 0), N - 1);
    int pos = atomicAdd(&cur[d >> 8], 1);
    tmp[pos] = ((unsigned)d << 16) | (unsigned)s;
  }
}

// D: per-bucket node-level scatter. col window ~8KB -> L1-resident full lines.
__global__ __launch_bounds__(256) void csr_final(const unsigned* __restrict__ tmp,
                                                 const int* __restrict__ rp,
                                                 u16* __restrict__ col, int N, int E) {
  __shared__ int cur[256];
  const int b = blockIdx.x;
  const int node0 = b * 256;
  const int nn = min(256, N - node0);
  if ((int)threadIdx.x < nn) cur[threadIdx.x] = rp[node0 + threadIdx.x];
  __syncthreads();
  const int k0 = rp[node0];
  const int k1 = rp[min(node0 + 256, N)];
  for (int k = k0 + (int)threadIdx.x; k < k1; k += 256) {
    unsigned e = tmp[k];
    int dl = (int)(e >> 16) - node0;      // 0..255
    int pos = atomicAdd(&cur[dl], 1);
    col[pos] = (u16)(e & 0xFFFFu);
  }
}

// ---------------- GEMM: C[M,Nt] = A[M,256] @ Bt[Nt,256]^T, bf16 in/out, fp32 acc
// LDS in fragment order: chunk c=(blk16*4 + k8)*16 + row16, 16B each; async staging.
template <int BN>
__global__ __launch_bounds__(256) void gemm_bt(const u16* __restrict__ A,
                                               const u16* __restrict__ Bt,
                                               u16* __restrict__ C, int Nt) {
  constexpr int K = 256;
  constexpr int BK = 32;
  constexpr int ACH = (128 * BK) / 8;
  constexpr int BCH = (BN * BK) / 8;
  constexpr int WAVES_N = BN / 64;
  constexpr int WAVES_M = 4 / WAVES_N;
  constexpr int WMF = 128 / (WAVES_M * 16);
  constexpr int WNF = BN / (WAVES_N * 16);

  __shared__ __align__(16) u16 As[128 * BK];
  __shared__ __align__(16) u16 Bs[BN * BK];

  const int tid = threadIdx.x;
  const int bm = blockIdx.x, bn = blockIdx.y;
  const int wid = tid >> 6, lane = tid & 63;
  const int wm = wid % WAVES_M, wn = wid / WAVES_M;
  const int m0 = wm * (WMF * 16), n0 = wn * (WNF * 16);
  const int r16 = lane & 15, quad = lane >> 4;

  f32x4 acc[WMF][WNF];
  const f32x4 fzero = {0.f, 0.f, 0.f, 0.f};
#pragma unroll
  for (int i = 0; i < WMF; ++i)
#pragma unroll
    for (int j = 0; j < WNF; ++j) acc[i][j] = fzero;

  const u16* Ag = A + (size_t)bm * 128 * K;
  const u16* Bg = Bt + (size_t)bn * BN * K;

  for (int kb = 0; kb < K; kb += BK) {
    __syncthreads();
#pragma unroll
    for (int r = 0; r < ACH / 256; ++r) {
      int c = tid + r * 256;
      int rr = (c >> 6) * 16 + (c & 15);
      int ko = ((c >> 4) & 3) * 8;
      async16(&As[c * 8], Ag + (size_t)rr * K + kb + ko);
    }
#pragma unroll
    for (int r = 0; r < BCH / 256; ++r) {
      int c = tid + r * 256;
      int rr = (c >> 6) * 16 + (c & 15);
      int ko = ((c >> 4) & 3) * 8;
      async16(&Bs[c * 8], Bg + (size_t)rr * K + kb + ko);
    }
    __syncthreads();
    bf16x8 af[WMF], bfr[WNF];
#pragma unroll
    for (int i = 0; i < WMF; ++i)
      af[i] = *(const bf16x8*)(&As[((m0 >> 4) + i) * 512 + lane * 8]);
#pragma unroll
    for (int j = 0; j < WNF; ++j)
      bfr[j] = *(const bf16x8*)(&Bs[((n0 >> 4) + j) * 512 + lane * 8]);
#pragma unroll
    for (int i = 0; i < WMF; ++i)
#pragma unroll
      for (int j = 0; j < WNF; ++j)
        acc[i][j] = __builtin_amdgcn_mfma_f32_16x16x32_bf16(af[i], bfr[j], acc[i][j], 0, 0, 0);
  }
#pragma unroll
  for (int i = 0; i < WMF; ++i)
#pragma unroll
    for (int j = 0; j < WNF; ++j) {
      int gr = bm * 128 + m0 + i * 16 + quad * 4;   // C/D: col=lane&15, row=quad*4+r
      int gc = bn * BN + n0 + j * 16 + r16;
#pragma unroll
      for (int r = 0; r < 4; ++r)
        C[(size_t)(gr + r) * Nt + gc] = f2bf(acc[i][j][r]);
    }
}

// ---------------- aggregation, d=256: half-wave = 1 edge, 4 loads deep ----------------
__global__ __launch_bounds__(256) void agg_d256(const u16* __restrict__ h,
                                                const int* __restrict__ rp,
                                                const u16* __restrict__ col,
                                                const float* __restrict__ dis,
                                                const float* __restrict__ bias,
                                                u16* __restrict__ out, int N) {
  const int wid = threadIdx.x >> 6, lane = threadIdx.x & 63;
  const int i = blockIdx.x * 4 + wid;
  if (i >= N) return;
  const int sub = lane >> 5;      // edge-pair selector
  const int l32 = lane & 31;
  const int c8 = l32 * 8;         // 8 features per lane
  const float di = dis[i];
  float a[8];
  {
    uint4 sv = *(const uint4*)(h + (size_t)i * 256 + c8);
    const float w = sub ? 0.f : di;     // self term once
    a[0] = w * bf2f((u16)sv.x); a[1] = w * bf2f((u16)(sv.x >> 16));
    a[2] = w * bf2f((u16)sv.y); a[3] = w * bf2f((u16)(sv.y >> 16));
    a[4] = w * bf2f((u16)sv.z); a[5] = w * bf2f((u16)(sv.z >> 16));
    a[6] = w * bf2f((u16)sv.w); a[7] = w * bf2f((u16)(sv.w >> 16));
  }
  const int e1 = rp[i + 1];
  for (int base = rp[i]; base < e1; base += 64) {
    int me = base + lane;
    int s_l = 0; float d_l = 0.f;
    if (me < e1) { s_l = (int)col[me]; d_l = dis[s_l]; }
    const int cnt = min(64, e1 - base);
    const int cntR = (cnt + 7) & ~7;
    for (int t = 0; t < cntR; t += 8) {    // 8 edges/iter, 4 loads deep per lane
      int sA = __shfl(s_l, t + sub, 64);      float dA = __shfl(d_l, t + sub, 64);
      int sB = __shfl(s_l, t + 2 + sub, 64);  float dB = __shfl(d_l, t + 2 + sub, 64);
      int sC = __shfl(s_l, t + 4 + sub, 64);  float dC = __shfl(d_l, t + 4 + sub, 64);
      int sD = __shfl(s_l, t + 6 + sub, 64);  float dD = __shfl(d_l, t + 6 + sub, 64);
      uint4 pA = *(const uint4*)(h + (size_t)sA * 256 + c8);
      uint4 pB = *(const uint4*)(h + (size_t)sB * 256 + c8);
      uint4 pC = *(const uint4*)(h + (size_t)sC * 256 + c8);
      uint4 pD = *(const uint4*)(h + (size_t)sD * 256 + c8);
      fma8(a, dA, pA); fma8(a, dB, pB); fma8(a, dC, pC); fma8(a, dD, pD);
    }
  }
#pragma unroll
  for (int k = 0; k < 8; ++k) a[k] += __shfl_xor(a[k], 32, 64);
  if (sub == 0) {
    float4 b0 = *(const float4*)(bias + c8);
    float4 b1 = *(const float4*)(bias + c8 + 4);
    float r0 = fmaxf(di * a[0] + b0.x, 0.f), r1 = fmaxf(di * a[1] + b0.y, 0.f);
    float r2 = fmaxf(di * a[2] + b0.z, 0.f), r3 = fmaxf(di * a[3] + b0.w, 0.f);
    float r4 = fmaxf(di * a[4] + b1.x, 0.f), r5 = fmaxf(di * a[5] + b1.y, 0.f);
    float r6 = fmaxf(di * a[6] + b1.z, 0.f), r7 = fmaxf(di * a[7] + b1.w, 0.f);
    uint4 ov;
    ov.x = (unsigned)f2bf(r0) | ((unsigned)f2bf(r1) << 16);
    ov.y = (unsigned)f2bf(r2) | ((unsigned)f2bf(r3) << 16);
    ov.z = (unsigned)f2bf(r4) | ((unsigned)f2bf(r5) << 16);
    ov.w = (unsigned)f2bf(r6) | ((unsigned)f2bf(r7) << 16);
    *(uint4*)(out + (size_t)i * 256 + c8) = ov;
  }
}

// final layer: h bf16 [N,64], out fp32 [N,64]. 8-lane group = 1 edge, 2 loads deep.
__global__ __launch_bounds__(256) void agg_d64(const u16* __restrict__ h,
                                               const int* __restrict__ rp,
                                               const u16* __restrict__ col,
                                               const float* __restrict__ dis,
                                               const float* __restrict__ bias,
                                               float* __restrict__ out, int N) {
  const int wid = threadIdx.x >> 6, lane = threadIdx.x & 63;
  const int i = blockIdx.x * 4 + wid;
  if (i >= N) return;
  const int grp = lane >> 3;      // edge slot 0..7
  const int l8 = lane & 7;
  const int c8 = l8 * 8;
  const float di = dis[i];
  float a[8];
  {
    uint4 sv = *(const uint4*)(h + (size_t)i * 64 + c8);
    const float w = (grp == 0) ? di : 0.f;
    a[0] = w * bf2f((u16)sv.x); a[1] = w * bf2f((u16)(sv.x >> 16));
    a[2] = w * bf2f((u16)sv.y); a[3] = w * bf2f((u16)(sv.y >> 16));
    a[4] = w * bf2f((u16)sv.z); a[5] = w * bf2f((u16)(sv.z >> 16));
    a[6] = w * bf2f((u16)sv.w); a[7] = w * bf2f((u16)(sv.w >> 16));
  }
  const int e1 = rp[i + 1];
  for (int base = rp[i]; base < e1; base += 64) {
    int me = base + lane;
    int s_l = 0; float d_l = 0.f;
    if (me < e1) { s_l = (int)col[me]; d_l = dis[s_l]; }
    const int cnt = min(64, e1 - base);
    const int cntR = (cnt + 15) & ~15;
    for (int t = 0; t < cntR; t += 16) {
      int sA = __shfl(s_l, t + grp, 64);       float dA = __shfl(d_l, t + grp, 64);
      int sB = __shfl(s_l, t + 8 + grp, 64);   float dB = __shfl(d_l, t + 8 + grp, 64);
      uint4 pA = *(const uint4*)(h + (size_t)sA * 64 + c8);
      uint4 pB = *(const uint4*)(h + (size_t)sB * 64 + c8);
      fma8(a, dA, pA); fma8(a, dB, pB);
    }
  }
#pragma unroll
  for (int k = 0; k < 8; ++k) a[k] += __shfl_xor(a[k], 8, 64);
#pragma unroll
  for (int k = 0; k < 8; ++k) a[k] += __shfl_xor(a[k], 16, 64);
#pragma unroll
  for (int k = 0; k < 8; ++k) a[k] += __shfl_xor(a[k], 32, 64);
  if (lane < 8) {
    float4 b0 = *(const float4*)(bias + c8);
    float4 b1 = *(const float4*)(bias + c8 + 4);
    float4 o0, o1;
    o0.x = di * a[0] + b0.x; o0.y = di * a[1] + b0.y;
    o0.z = di * a[2] + b0.z; o0.w = di * a[3] + b0.w;
    o1.x = di * a[4] + b1.x; o1.y = di * a[5] + b1.y;
    o1.z = di * a[6] + b1.z; o1.w = di * a[7] + b1.w;
    *(float4*)(out + (size_t)i * 64 + c8) = o0;
    *(float4*)(out + (size_t)i * 64 + c8 + 4) = o1;
  }
}

// ---------------- launch ----------------
extern "C" void kernel_launch(void* const* d_in, const int* in_sizes, int n_in,
                              void* d_out, int out_size, void* d_ws, size_t ws_size,
                              hipStream_t stream) {
  if (n_in < 8) return;
  const float* x = (const float*)d_in[0];
  const void* eptr = d_in[1];
  const float* W1 = (const float*)d_in[2];
  const float* b1 = (const float*)d_in[3];
  const float* W2 = (const float*)d_in[4];
  const float* b2 = (const float*)d_in[5];
  const float* W3 = (const float*)d_in[6];
  const float* b3 = (const float*)d_in[7];
  float* out = (float*)d_out;

  const int DIN = 256, DH = 256;
  const int N = in_sizes[0] / DIN;       // 50000
  const int E = in_sizes[1] / 2;         // 800000
  const int DOUT = in_sizes[6] / DH;     // 64
  const int MT = (N + 127) / 128;        // 391
  const int Mpad = MT * 128;
  const int nbuck = (N + 255) >> 8;      // 196

  auto rnd = [](size_t b) { return (b + 255) & ~(size_t)255; };
  size_t required = 0;
  required += rnd((size_t)Mpad * DH * 2) * 2;        // xpad + hbuf
  required += rnd((size_t)E * 2);                    // col (u16)
  required += rnd((size_t)E * 4);                    // tmp (packed pairs)
  required += rnd((size_t)(N + 1) * 4);              // rp
  required += rnd((size_t)N * 4) * 2;                // indeg, dis
  required += rnd((size_t)DIN * DH * 2);             // wt1
  required += rnd((size_t)DH * DH * 2);              // wt2
  required += rnd((size_t)DH * DOUT * 2);            // wt3
  required += rnd((size_t)256 * NCHUNK * 4) * 2;     // cnt + off
  required += 512;                                   // bsums
  if (ws_size < required || N > 65536) {
    zero_f32<<<(out_size + 255) / 256, 256, 0, stream>>>(out, out_size);
    return;
  }

  char* ws = (char*)d_ws;
  size_t off0 = 0;
  auto alloc = [&](size_t bytes) {
    char* p = ws + off0;
    off0 = (off0 + bytes + 255) & ~(size_t)255;
    return p;
  };
  u16* xpad = (u16*)alloc((size_t)Mpad * DH * 2);
  u16* hbuf = (u16*)alloc((size_t)Mpad * DH * 2);
  u16* colb = (u16*)alloc((size_t)E * 2);
  unsigned* tmpb = (unsigned*)alloc((size_t)E * 4);
  int* rp = (int*)alloc((size_t)(N + 1) * 4);
  int* indeg = (int*)alloc((size_t)N * 4);
  float* dis = (float*)alloc((size_t)N * 4);
  u16* wt1 = (u16*)alloc((size_t)DIN * DH * 2);
  u16* wt2 = (u16*)alloc((size_t)DH * DH * 2);
  u16* wt3 = (u16*)alloc((size_t)DH * DOUT * 2);
  int* cnt = (int*)alloc((size_t)256 * NCHUNK * 4);
  int* offs = (int*)alloc((size_t)256 * NCHUNK * 4);
  int* bsums = (int*)alloc(64 * 4);

  hipMemsetAsync(indeg, 0, (size_t)N * 4, stream);

  const int n_tot4 = Mpad * DH / 4;
  const int nb_cvt = (n_tot4 + 255) / 256;
  const int nb_deg = (E + 255) / 256;
  const int nb_w1 = (DIN * DH + 255) / 256;
  const int nb_w2 = (DH * DH + 255) / 256;
  const int nb_w3 = (DH * DOUT + 255) / 256;
  prep_fused<<<nb_cvt + nb_deg + nb_w1 + nb_w2 + nb_w3, 256, 0, stream>>>(
      (const float4*)x, (ushort4*)xpad, N * DH / 4, n_tot4,
      eptr, indeg, E, N, W1, wt1, W2, wt2, W3, wt3,
      DIN, DH, DOUT, nb_cvt, nb_deg, nb_w1, nb_w2);

  const int nsb = (N + 1023) / 1024;
  scan_block<<<nsb, 1024, 0, stream>>>(indeg, rp, bsums, N);
  if (nsb <= 64)
    scan_tops_wave<<<1, 64, 0, stream>>>(bsums, nsb);
  else
    scan_tops_serial<<<1, 64, 0, stream>>>(bsums, nsb);
  scan_fix<<<(N + 255) / 256, 256, 0, stream>>>(rp, bsums, indeg, dis, N, E);

  // bucketed CSR build
  csr_hist<<<NCHUNK, 256, 0, stream>>>(eptr, cnt, E, N);
  csr_scan2<<<nbuck, 64, 0, stream>>>(cnt, rp, offs, N);
  csr_bucket<<<NCHUNK, 256, 0, stream>>>(eptr, offs, tmpb, E, N);
  csr_final<<<nbuck, 256, 0, stream>>>(tmpb, rp, colb, N, E);

  // layer 1
  gemm_bt<128><<<dim3(MT, DH / 128), 256, 0, stream>>>(xpad, wt1, hbuf, DH);
  agg_d256<<<(N + 3) / 4, 256, 0, stream>>>(hbuf, rp, colb, dis, b1, xpad, N);
  // layer 2
  gemm_bt<128><<<dim3(MT, DH / 128), 256, 0, stream>>>(xpad, wt2, hbuf, DH);
  agg_d256<<<(N + 3) / 4, 256, 0, stream>>>(hbuf, rp, colb, dis, b2, xpad, N);
  // layer 3
  gemm_bt<64><<<dim3(MT, DOUT / 64), 256, 0, stream>>>(xpad, wt3, hbuf, DOUT);
  agg_d64<<<(N + 3) / 4, 256, 0, stream>>>(hbuf, rp, colb, dis, b3, out, N);
}

// Round 8
// 385.493 us; speedup vs baseline: 1.1179x; 1.0176x over previous
//
#include <hip/hip_runtime.h>
#include <cstdint>
#include <cstddef>

typedef unsigned short u16;
typedef _Float16 f16x8 __attribute__((ext_vector_type(8)));
typedef _Float16 h2 __attribute__((ext_vector_type(2)));
typedef float f32x4 __attribute__((ext_vector_type(4)));

__device__ __forceinline__ float h2f(u16 u) {
  return (float)__builtin_bit_cast(_Float16, u);
}
__device__ __forceinline__ u16 f2h(float f) {
  return __builtin_bit_cast(u16, (_Float16)f);
}

// async 16B global -> LDS (gfx950)
__device__ __forceinline__ void async16(u16* lds, const u16* g) {
  __builtin_amdgcn_global_load_lds(
      (const __attribute__((address_space(1))) unsigned int*)g,
      (__attribute__((address_space(3))) unsigned int*)lds, 16, 0, 0);
}

// fp32 unpack-fma (used by final layer for fp32 accumulation)
__device__ __forceinline__ void fma8(float* a, float d, uint4 p) {
  a[0] += d * h2f((u16)p.x); a[1] += d * h2f((u16)(p.x >> 16));
  a[2] += d * h2f((u16)p.y); a[3] += d * h2f((u16)(p.y >> 16));
  a[4] += d * h2f((u16)p.z); a[5] += d * h2f((u16)(p.z >> 16));
  a[6] += d * h2f((u16)p.w); a[7] += d * h2f((u16)(p.w >> 16));
}

// packed f16 fma: acc[j] += h2(p word j) * w  (v_pk_fma_f16)
__device__ __forceinline__ void pkfma4(h2* acc, h2 w, uint4 p) {
  acc[0] += __builtin_bit_cast(h2, p.x) * w;
  acc[1] += __builtin_bit_cast(h2, p.y) * w;
  acc[2] += __builtin_bit_cast(h2, p.z) * w;
  acc[3] += __builtin_bit_cast(h2, p.w) * w;
}

// per-wave int64-vs-int32 edge dtype detection (first 1KB, L2-hot)
__device__ __forceinline__ int wave_is64(const void* ep) {
  const unsigned* p = (const unsigned*)ep;
  const int lane = threadIdx.x & 63;
  unsigned v = p[2 * lane + 1] | p[2 * (lane + 64) + 1];
  unsigned long long bal = __ballot(v != 0u);
  return (bal == 0ull) ? 1 : 0;
}

__device__ __forceinline__ int edge_at(const void* ep, int is64, long long idx) {
  if (is64) return (int)((const long long*)ep)[idx];
  return ((const int*)ep)[idx];
}

// ---------------- diagnostics / fallback ----------------
__global__ void zero_f32(float* p, int n) {
  int i = blockIdx.x * 256 + threadIdx.x;
  if (i < n) p[i] = 0.f;
}

// ---------------- fused prep: cvt_pad + count_deg + 3x transpose_w ----------------
__global__ __launch_bounds__(256) void prep_fused(
    const float4* __restrict__ x, ushort4* __restrict__ xpad, int n_src4, int n_tot4,
    const void* __restrict__ ep, int* __restrict__ indeg, int E, int N,
    const float* __restrict__ W1, u16* __restrict__ wt1,
    const float* __restrict__ W2, u16* __restrict__ wt2,
    const float* __restrict__ W3, u16* __restrict__ wt3,
    int DIN, int DH, int DOUT,
    int nb_cvt, int nb_deg, int nb_w1, int nb_w2) {
  int b = blockIdx.x;
  if (b < nb_cvt) {                       // fp32 -> f16 convert + pad
    int i = b * 256 + threadIdx.x;
    if (i < n_tot4) {
      ushort4 o = {0, 0, 0, 0};
      if (i < n_src4) {
        float4 v = x[i];
        o.x = f2h(v.x); o.y = f2h(v.y); o.z = f2h(v.z); o.w = f2h(v.w);
      }
      xpad[i] = o;
    }
    return;
  }
  b -= nb_cvt;
  if (b < nb_deg) {                       // in-degree count
    int is64 = wave_is64(ep);
    int e = b * 256 + threadIdx.x;
    if (e < E) {
      int d = edge_at(ep, is64, (long long)E + e);
      d = min(max(d, 0), N - 1);
      atomicAdd(&indeg[d], 1);
    }
    return;
  }
  b -= nb_deg;
  if (b < nb_w1) {                        // wt1[n*DIN+k] = W1[k*DH+n]
    int idx = b * 256 + threadIdx.x;
    if (idx < DIN * DH) {
      int n = idx / DIN, k = idx % DIN;
      wt1[idx] = f2h(W1[k * DH + n]);
    }
    return;
  }
  b -= nb_w1;
  if (b < nb_w2) {                        // wt2[n*DH+k] = W2[k*DH+n]
    int idx = b * 256 + threadIdx.x;
    if (idx < DH * DH) {
      int n = idx / DH, k = idx % DH;
      wt2[idx] = f2h(W2[k * DH + n]);
    }
    return;
  }
  b -= nb_w2;
  {                                       // wt3[n*DH+k] = W3[k*DOUT+n]
    int idx = b * 256 + threadIdx.x;
    if (idx < DH * DOUT) {
      int n = idx / DH, k = idx % DH;
      wt3[idx] = f2h(W3[k * DOUT + n]);
    }
  }
}

// ---------------- parallel CSR scan chain ----------------
__global__ void scan_block(const int* __restrict__ indeg, int* __restrict__ rp,
                           int* __restrict__ bsums, int N) {
  __shared__ int tmp[1024];
  const int t = threadIdx.x;
  const int i = blockIdx.x * 1024 + t;
  int v = (i < N) ? indeg[i] : 0;
  tmp[t] = v;
  __syncthreads();
  for (int off = 1; off < 1024; off <<= 1) {
    int add = (t >= off) ? tmp[t - off] : 0;
    __syncthreads();
    tmp[t] += add;
    __syncthreads();
  }
  if (i < N) rp[i] = tmp[t] - v;          // exclusive
  if (t == 0) bsums[blockIdx.x] = tmp[1023];
}

__global__ void scan_tops_wave(int* bsums, int nb) {
  const int lane = threadIdx.x & 63;
  int v = (lane < nb) ? bsums[lane] : 0;
  int inc = v;
  for (int off = 1; off < 64; off <<= 1) {
    int u = __shfl_up(inc, off, 64);
    if (lane >= off) inc += u;
  }
  if (lane < nb) bsums[lane] = inc - v;
}

__global__ void scan_tops_serial(int* bsums, int nb) {
  if (threadIdx.x == 0 && blockIdx.x == 0) {
    int run = 0;
    for (int b = 0; b < nb; ++b) { int v = bsums[b]; bsums[b] = run; run += v; }
  }
}

__global__ void scan_fix(int* __restrict__ rp, const int* __restrict__ bsums,
                         const int* __restrict__ indeg,
                         float* __restrict__ dis, int N, int E) {
  const int i = blockIdx.x * 256 + threadIdx.x;
  if (i == 0) rp[N] = E;
  if (i >= N) return;
  int r = rp[i] + bsums[i >> 10];
  rp[i] = r;
  dis[i] = rsqrtf((float)(indeg[i] + 1));  // +1 = self loop
}

// ---------------- bucketed CSR build (coalesced writes; needs N <= 65536) -----
#define NCHUNK 64

__global__ __launch_bounds__(256) void csr_hist(const void* __restrict__ ep,
                                                int* __restrict__ cnt, int E, int N) {
  __shared__ int h[256];
  h[threadIdx.x] = 0;
  __syncthreads();
  int is64 = wave_is64(ep);
  const int chunk = blockIdx.x;
  const int per = (E + NCHUNK - 1) / NCHUNK;
  const int e0 = chunk * per, e1 = min(e0 + per, E);
  for (int e = e0 + threadIdx.x; e < e1; e += 256) {
    int d = edge_at(ep, is64, (long long)E + e);
    d = min(max(d, 0), N - 1);
    atomicAdd(&h[d >> 8], 1);
  }
  __syncthreads();
  cnt[threadIdx.x * NCHUNK + chunk] = h[threadIdx.x];
}

__global__ void csr_scan2(const int* __restrict__ cnt, const int* __restrict__ rp,
                          int* __restrict__ off, int N) {
  const int b = blockIdx.x;
  const int lane = threadIdx.x & 63;       // NCHUNK == 64
  int v = cnt[b * NCHUNK + lane];
  int inc = v;
#pragma unroll
  for (int o = 1; o < 64; o <<= 1) {
    int u = __shfl_up(inc, o, 64);
    if (lane >= o) inc += u;
  }
  const int base = rp[min(b * 256, N)];
  off[b * NCHUNK + lane] = base + inc - v;
}

__global__ __launch_bounds__(256) void csr_bucket(const void* __restrict__ ep,
                                                  const int* __restrict__ off,
                                                  unsigned* __restrict__ tmp,
                                                  int E, int N) {
  __shared__ int cur[256];
  const int chunk = blockIdx.x;
  const int nbuck = (N + 255) >> 8;
  if ((int)threadIdx.x < nbuck) cur[threadIdx.x] = off[threadIdx.x * NCHUNK + chunk];
  __syncthreads();
  int is64 = wave_is64(ep);
  const int per = (E + NCHUNK - 1) / NCHUNK;
  const int e0 = chunk * per, e1 = min(e0 + per, E);
  for (int e = e0 + threadIdx.x; e < e1; e += 256) {
    int s = edge_at(ep, is64, e);
    int d = edge_at(ep, is64, (long long)E + e);
    s = min(max(s, 0), N - 1);
    d = min(max(d, 0), N - 1);
    int pos = atomicAdd(&cur[d >> 8], 1);
    tmp[pos] = ((unsigned)d << 16) | (unsigned)s;
  }
}

__global__ __launch_bounds__(256) void csr_final(const unsigned* __restrict__ tmp,
                                                 const int* __restrict__ rp,
                                                 u16* __restrict__ col, int N, int E) {
  __shared__ int cur[256];
  const int b = blockIdx.x;
  const int node0 = b * 256;
  const int nn = min(256, N - node0);
  if ((int)threadIdx.x < nn) cur[threadIdx.x] = rp[node0 + threadIdx.x];
  __syncthreads();
  const int k0 = rp[node0];
  const int k1 = rp[min(node0 + 256, N)];
  for (int k = k0 + (int)threadIdx.x; k < k1; k += 256) {
    unsigned e = tmp[k];
    int dl = (int)(e >> 16) - node0;
    int pos = atomicAdd(&cur[dl], 1);
    col[pos] = (u16)(e & 0xFFFFu);
  }
}

// ---------------- GEMM: C[M,Nt] = A[M,256] @ Bt[Nt,256]^T, f16 in/out, fp32 acc
template <int BN>
__global__ __launch_bounds__(256) void gemm_bt(const u16* __restrict__ A,
                                               const u16* __restrict__ Bt,
                                               u16* __restrict__ C, int Nt) {
  constexpr int K = 256;
  constexpr int BK = 32;
  constexpr int ACH = (128 * BK) / 8;
  constexpr int BCH = (BN * BK) / 8;
  constexpr int WAVES_N = BN / 64;
  constexpr int WAVES_M = 4 / WAVES_N;
  constexpr int WMF = 128 / (WAVES_M * 16);
  constexpr int WNF = BN / (WAVES_N * 16);

  __shared__ __align__(16) u16 As[128 * BK];
  __shared__ __align__(16) u16 Bs[BN * BK];

  const int tid = threadIdx.x;
  const int bm = blockIdx.x, bn = blockIdx.y;
  const int wid = tid >> 6, lane = tid & 63;
  const int wm = wid % WAVES_M, wn = wid / WAVES_M;
  const int m0 = wm * (WMF * 16), n0 = wn * (WNF * 16);
  const int r16 = lane & 15, quad = lane >> 4;

  f32x4 acc[WMF][WNF];
  const f32x4 fzero = {0.f, 0.f, 0.f, 0.f};
#pragma unroll
  for (int i = 0; i < WMF; ++i)
#pragma unroll
    for (int j = 0; j < WNF; ++j) acc[i][j] = fzero;

  const u16* Ag = A + (size_t)bm * 128 * K;
  const u16* Bg = Bt + (size_t)bn * BN * K;

  for (int kb = 0; kb < K; kb += BK) {
    __syncthreads();
#pragma unroll
    for (int r = 0; r < ACH / 256; ++r) {
      int c = tid + r * 256;
      int rr = (c >> 6) * 16 + (c & 15);
      int ko = ((c >> 4) & 3) * 8;
      async16(&As[c * 8], Ag + (size_t)rr * K + kb + ko);
    }
#pragma unroll
    for (int r = 0; r < BCH / 256; ++r) {
      int c = tid + r * 256;
      int rr = (c >> 6) * 16 + (c & 15);
      int ko = ((c >> 4) & 3) * 8;
      async16(&Bs[c * 8], Bg + (size_t)rr * K + kb + ko);
    }
    __syncthreads();
    f16x8 af[WMF], bfr[WNF];
#pragma unroll
    for (int i = 0; i < WMF; ++i)
      af[i] = *(const f16x8*)(&As[((m0 >> 4) + i) * 512 + lane * 8]);
#pragma unroll
    for (int j = 0; j < WNF; ++j)
      bfr[j] = *(const f16x8*)(&Bs[((n0 >> 4) + j) * 512 + lane * 8]);
#pragma unroll
    for (int i = 0; i < WMF; ++i)
#pragma unroll
      for (int j = 0; j < WNF; ++j)
        acc[i][j] = __builtin_amdgcn_mfma_f32_16x16x32_f16(af[i], bfr[j], acc[i][j], 0, 0, 0);
  }
#pragma unroll
  for (int i = 0; i < WMF; ++i)
#pragma unroll
    for (int j = 0; j < WNF; ++j) {
      int gr = bm * 128 + m0 + i * 16 + quad * 4;   // C/D: col=lane&15, row=quad*4+r
      int gc = bn * BN + n0 + j * 16 + r16;
#pragma unroll
      for (int r = 0; r < 4; ++r)
        C[(size_t)(gr + r) * Nt + gc] = f2h(acc[i][j][r]);
    }
}

// ---------------- aggregation, d=256: half-wave = 1 edge, 4 loads deep,
// packed f16 accumulation (v_pk_fma_f16), fp32 cross-half merge + epilogue ----
__global__ __launch_bounds__(256) void agg_d256(const u16* __restrict__ h,
                                                const int* __restrict__ rp,
                                                const u16* __restrict__ col,
                                                const float* __restrict__ dis,
                                                const float* __restrict__ bias,
                                                u16* __restrict__ out, int N) {
  const int wid = threadIdx.x >> 6, lane = threadIdx.x & 63;
  const int i = blockIdx.x * 4 + wid;
  if (i >= N) return;
  const int sub = lane >> 5;      // edge-pair selector
  const int l32 = lane & 31;
  const int c8 = l32 * 8;         // 8 features per lane
  const float di = dis[i];
  h2 acc[4];
  {
    uint4 sv = *(const uint4*)(h + (size_t)i * 256 + c8);
    const _Float16 w = (_Float16)(sub ? 0.f : di);   // self term once
    const h2 ws = {w, w};
    acc[0] = __builtin_bit_cast(h2, sv.x) * ws;
    acc[1] = __builtin_bit_cast(h2, sv.y) * ws;
    acc[2] = __builtin_bit_cast(h2, sv.z) * ws;
    acc[3] = __builtin_bit_cast(h2, sv.w) * ws;
  }
  const int e1 = rp[i + 1];
  for (int base = rp[i]; base < e1; base += 64) {
    int me = base + lane;
    int s_l = 0; float d_l = 0.f;
    if (me < e1) { s_l = (int)col[me]; d_l = dis[s_l]; }
    const int cnt = min(64, e1 - base);
    const int cntR = (cnt + 7) & ~7;
    for (int t = 0; t < cntR; t += 8) {    // 8 edges/iter, 4 loads deep per lane
      int sA = __shfl(s_l, t + sub, 64);      float dA = __shfl(d_l, t + sub, 64);
      int sB = __shfl(s_l, t + 2 + sub, 64);  float dB = __shfl(d_l, t + 2 + sub, 64);
      int sC = __shfl(s_l, t + 4 + sub, 64);  float dC = __shfl(d_l, t + 4 + sub, 64);
      int sD = __shfl(s_l, t + 6 + sub, 64);  float dD = __shfl(d_l, t + 6 + sub, 64);
      uint4 pA = *(const uint4*)(h + (size_t)sA * 256 + c8);
      uint4 pB = *(const uint4*)(h + (size_t)sB * 256 + c8);
      uint4 pC = *(const uint4*)(h + (size_t)sC * 256 + c8);
      uint4 pD = *(const uint4*)(h + (size_t)sD * 256 + c8);
      _Float16 hA = (_Float16)dA, hB = (_Float16)dB;
      _Float16 hC = (_Float16)dC, hD = (_Float16)dD;
      h2 wA = {hA, hA}, wB = {hB, hB}, wC = {hC, hC}, wD = {hD, hD};
      pkfma4(acc, wA, pA); pkfma4(acc, wB, pB);
      pkfma4(acc, wC, pC); pkfma4(acc, wD, pD);
    }
  }
  // f16 -> fp32, merge halves in fp32
  float a[8];
#pragma unroll
  for (int j = 0; j < 4; ++j) {
    a[2 * j] = (float)acc[j].x;
    a[2 * j + 1] = (float)acc[j].y;
  }
#pragma unroll
  for (int k = 0; k < 8; ++k) a[k] += __shfl_xor(a[k], 32, 64);
  if (sub == 0) {
    float4 b0 = *(const float4*)(bias + c8);
    float4 b1 = *(const float4*)(bias + c8 + 4);
    float r0 = fmaxf(di * a[0] + b0.x, 0.f), r1 = fmaxf(di * a[1] + b0.y, 0.f);
    float r2 = fmaxf(di * a[2] + b0.z, 0.f), r3 = fmaxf(di * a[3] + b0.w, 0.f);
    float r4 = fmaxf(di * a[4] + b1.x, 0.f), r5 = fmaxf(di * a[5] + b1.y, 0.f);
    float r6 = fmaxf(di * a[6] + b1.z, 0.f), r7 = fmaxf(di * a[7] + b1.w, 0.f);
    uint4 ov;
    ov.x = (unsigned)f2h(r0) | ((unsigned)f2h(r1) << 16);
    ov.y = (unsigned)f2h(r2) | ((unsigned)f2h(r3) << 16);
    ov.z = (unsigned)f2h(r4) | ((unsigned)f2h(r5) << 16);
    ov.w = (unsigned)f2h(r6) | ((unsigned)f2h(r7) << 16);
    *(uint4*)(out + (size_t)i * 256 + c8) = ov;
  }
}

// final layer: h f16 [N,64], out fp32 [N,64], fp32 accumulation. 8-lane group/edge.
__global__ __launch_bounds__(256) void agg_d64(const u16* __restrict__ h,
                                               const int* __restrict__ rp,
                                               const u16* __restrict__ col,
                                               const float* __restrict__ dis,
                                               const float* __restrict__ bias,
                                               float* __restrict__ out, int N) {
  const int wid = threadIdx.x >> 6, lane = threadIdx.x & 63;
  const int i = blockIdx.x * 4 + wid;
  if (i >= N) return;
  const int grp = lane >> 3;      // edge slot 0..7
  const int l8 = lane & 7;
  const int c8 = l8 * 8;
  const float di = dis[i];
  float a[8];
  {
    uint4 sv = *(const uint4*)(h + (size_t)i * 64 + c8);
    const float w = (grp == 0) ? di : 0.f;
    a[0] = w * h2f((u16)sv.x); a[1] = w * h2f((u16)(sv.x >> 16));
    a[2] = w * h2f((u16)sv.y); a[3] = w * h2f((u16)(sv.y >> 16));
    a[4] = w * h2f((u16)sv.z); a[5] = w * h2f((u16)(sv.z >> 16));
    a[6] = w * h2f((u16)sv.w); a[7] = w * h2f((u16)(sv.w >> 16));
  }
  const int e1 = rp[i + 1];
  for (int base = rp[i]; base < e1; base += 64) {
    int me = base + lane;
    int s_l = 0; float d_l = 0.f;
    if (me < e1) { s_l = (int)col[me]; d_l = dis[s_l]; }
    const int cnt = min(64, e1 - base);
    const int cntR = (cnt + 15) & ~15;
    for (int t = 0; t < cntR; t += 16) {
      int sA = __shfl(s_l, t + grp, 64);       float dA = __shfl(d_l, t + grp, 64);
      int sB = __shfl(s_l, t + 8 + grp, 64);   float dB = __shfl(d_l, t + 8 + grp, 64);
      uint4 pA = *(const uint4*)(h + (size_t)sA * 64 + c8);
      uint4 pB = *(const uint4*)(h + (size_t)sB * 64 + c8);
      fma8(a, dA, pA); fma8(a, dB, pB);
    }
  }
#pragma unroll
  for (int k = 0; k < 8; ++k) a[k] += __shfl_xor(a[k], 8, 64);
#pragma unroll
  for (int k = 0; k < 8; ++k) a[k] += __shfl_xor(a[k], 16, 64);
#pragma unroll
  for (int k = 0; k < 8; ++k) a[k] += __shfl_xor(a[k], 32, 64);
  if (lane < 8) {
    float4 b0 = *(const float4*)(bias + c8);
    float4 b1 = *(const float4*)(bias + c8 + 4);
    float4 o0, o1;
    o0.x = di * a[0] + b0.x; o0.y = di * a[1] + b0.y;
    o0.z = di * a[2] + b0.z; o0.w = di * a[3] + b0.w;
    o1.x = di * a[4] + b1.x; o1.y = di * a[5] + b1.y;
    o1.z = di * a[6] + b1.z; o1.w = di * a[7] + b1.w;
    *(float4*)(out + (size_t)i * 64 + c8) = o0;
    *(float4*)(out + (size_t)i * 64 + c8 + 4) = o1;
  }
}

// ---------------- launch ----------------
extern "C" void kernel_launch(void* const* d_in, const int* in_sizes, int n_in,
                              void* d_out, int out_size, void* d_ws, size_t ws_size,
                              hipStream_t stream) {
  if (n_in < 8) return;
  const float* x = (const float*)d_in[0];
  const void* eptr = d_in[1];
  const float* W1 = (const float*)d_in[2];
  const float* b1 = (const float*)d_in[3];
  const float* W2 = (const float*)d_in[4];
  const float* b2 = (const float*)d_in[5];
  const float* W3 = (const float*)d_in[6];
  const float* b3 = (const float*)d_in[7];
  float* out = (float*)d_out;

  const int DIN = 256, DH = 256;
  const int N = in_sizes[0] / DIN;       // 50000
  const int E = in_sizes[1] / 2;         // 800000
  const int DOUT = in_sizes[6] / DH;     // 64
  const int MT = (N + 127) / 128;        // 391
  const int Mpad = MT * 128;
  const int nbuck = (N + 255) >> 8;      // 196

  auto rnd = [](size_t b) { return (b + 255) & ~(size_t)255; };
  size_t required = 0;
  required += rnd((size_t)Mpad * DH * 2) * 2;        // xpad + hbuf
  required += rnd((size_t)E * 2);                    // col (u16)
  required += rnd((size_t)E * 4);                    // tmp (packed pairs)
  required += rnd((size_t)(N + 1) * 4);              // rp
  required += rnd((size_t)N * 4) * 2;                // indeg, dis
  required += rnd((size_t)DIN * DH * 2);             // wt1
  required += rnd((size_t)DH * DH * 2);              // wt2
  required += rnd((size_t)DH * DOUT * 2);            // wt3
  required += rnd((size_t)256 * NCHUNK * 4) * 2;     // cnt + off
  required += 512;                                   // bsums
  if (ws_size < required || N > 65536) {
    zero_f32<<<(out_size + 255) / 256, 256, 0, stream>>>(out, out_size);
    return;
  }

  char* ws = (char*)d_ws;
  size_t off0 = 0;
  auto alloc = [&](size_t bytes) {
    char* p = ws + off0;
    off0 = (off0 + bytes + 255) & ~(size_t)255;
    return p;
  };
  u16* xpad = (u16*)alloc((size_t)Mpad * DH * 2);
  u16* hbuf = (u16*)alloc((size_t)Mpad * DH * 2);
  u16* colb = (u16*)alloc((size_t)E * 2);
  unsigned* tmpb = (unsigned*)alloc((size_t)E * 4);
  int* rp = (int*)alloc((size_t)(N + 1) * 4);
  int* indeg = (int*)alloc((size_t)N * 4);
  float* dis = (float*)alloc((size_t)N * 4);
  u16* wt1 = (u16*)alloc((size_t)DIN * DH * 2);
  u16* wt2 = (u16*)alloc((size_t)DH * DH * 2);
  u16* wt3 = (u16*)alloc((size_t)DH * DOUT * 2);
  int* cnt = (int*)alloc((size_t)256 * NCHUNK * 4);
  int* offs = (int*)alloc((size_t)256 * NCHUNK * 4);
  int* bsums = (int*)alloc(64 * 4);

  hipMemsetAsync(indeg, 0, (size_t)N * 4, stream);

  const int n_tot4 = Mpad * DH / 4;
  const int nb_cvt = (n_tot4 + 255) / 256;
  const int nb_deg = (E + 255) / 256;
  const int nb_w1 = (DIN * DH + 255) / 256;
  const int nb_w2 = (DH * DH + 255) / 256;
  const int nb_w3 = (DH * DOUT + 255) / 256;
  prep_fused<<<nb_cvt + nb_deg + nb_w1 + nb_w2 + nb_w3, 256, 0, stream>>>(
      (const float4*)x, (ushort4*)xpad, N * DH / 4, n_tot4,
      eptr, indeg, E, N, W1, wt1, W2, wt2, W3, wt3,
      DIN, DH, DOUT, nb_cvt, nb_deg, nb_w1, nb_w2);

  const int nsb = (N + 1023) / 1024;
  scan_block<<<nsb, 1024, 0, stream>>>(indeg, rp, bsums, N);
  if (nsb <= 64)
    scan_tops_wave<<<1, 64, 0, stream>>>(bsums, nsb);
  else
    scan_tops_serial<<<1, 64, 0, stream>>>(bsums, nsb);
  scan_fix<<<(N + 255) / 256, 256, 0, stream>>>(rp, bsums, indeg, dis, N, E);

  // bucketed CSR build
  csr_hist<<<NCHUNK, 256, 0, stream>>>(eptr, cnt, E, N);
  csr_scan2<<<nbuck, 64, 0, stream>>>(cnt, rp, offs, N);
  csr_bucket<<<NCHUNK, 256, 0, stream>>>(eptr, offs, tmpb, E, N);
  csr_final<<<nbuck, 256, 0, stream>>>(tmpb, rp, colb, N, E);

  // layer 1
  gemm_bt<128><<<dim3(MT, DH / 128), 256, 0, stream>>>(xpad, wt1, hbuf, DH);
  agg_d256<<<(N + 3) / 4, 256, 0, stream>>>(hbuf, rp, colb, dis, b1, xpad, N);
  // layer 2
  gemm_bt<128><<<dim3(MT, DH / 128), 256, 0, stream>>>(xpad, wt2, hbuf, DH);
  agg_d256<<<(N + 3) / 4, 256, 0, stream>>>(hbuf, rp, colb, dis, b2, xpad, N);
  // layer 3
  gemm_bt<64><<<dim3(MT, DOUT / 64), 256, 0, stream>>>(xpad, wt3, hbuf, DOUT);
  agg_d64<<<(N + 3) / 4, 256, 0, stream>>>(hbuf, rp, colb, dis, b3, out, N);
}

// Round 9
// 345.976 us; speedup vs baseline: 1.2456x; 1.1142x over previous
//
#include <hip/hip_runtime.h>
#include <cstdint>
#include <cstddef>

typedef unsigned short u16;
typedef _Float16 f16x8 __attribute__((ext_vector_type(8)));
typedef _Float16 h2 __attribute__((ext_vector_type(2)));
typedef float f32x4 __attribute__((ext_vector_type(4)));

__device__ __forceinline__ float h2f(u16 u) {
  return (float)__builtin_bit_cast(_Float16, u);
}
__device__ __forceinline__ u16 f2h(float f) {
  return __builtin_bit_cast(u16, (_Float16)f);
}

// async 16B global -> LDS (gfx950)
__device__ __forceinline__ void async16(u16* lds, const u16* g) {
  __builtin_amdgcn_global_load_lds(
      (const __attribute__((address_space(1))) unsigned int*)g,
      (__attribute__((address_space(3))) unsigned int*)lds, 16, 0, 0);
}

// fp32 unpack-fma (final layer, fp32 accumulation)
__device__ __forceinline__ void fma8(float* a, float d, uint4 p) {
  a[0] += d * h2f((u16)p.x); a[1] += d * h2f((u16)(p.x >> 16));
  a[2] += d * h2f((u16)p.y); a[3] += d * h2f((u16)(p.y >> 16));
  a[4] += d * h2f((u16)p.z); a[5] += d * h2f((u16)(p.z >> 16));
  a[6] += d * h2f((u16)p.w); a[7] += d * h2f((u16)(p.w >> 16));
}

// packed f16 fma: acc[j] += h2(p word j) * w
__device__ __forceinline__ void pkfma4(h2* acc, h2 w, uint4 p) {
  acc[0] += __builtin_bit_cast(h2, p.x) * w;
  acc[1] += __builtin_bit_cast(h2, p.y) * w;
  acc[2] += __builtin_bit_cast(h2, p.z) * w;
  acc[3] += __builtin_bit_cast(h2, p.w) * w;
}

// per-wave int64-vs-int32 edge dtype detection (first 1KB, L2-hot)
__device__ __forceinline__ int wave_is64(const void* ep) {
  const unsigned* p = (const unsigned*)ep;
  const int lane = threadIdx.x & 63;
  unsigned v = p[2 * lane + 1] | p[2 * (lane + 64) + 1];
  unsigned long long bal = __ballot(v != 0u);
  return (bal == 0ull) ? 1 : 0;
}

__device__ __forceinline__ int edge_at(const void* ep, int is64, long long idx) {
  if (is64) return (int)((const long long*)ep)[idx];
  return ((const int*)ep)[idx];
}

// ---------------- diagnostics / fallback ----------------
__global__ void zero_f32(float* p, int n) {
  int i = blockIdx.x * 256 + threadIdx.x;
  if (i < n) p[i] = 0.f;
}

// ---------------- fused prep: cvt_pad + 3x transpose_w ----------------
__global__ __launch_bounds__(256) void prep_fused(
    const float4* __restrict__ x, ushort4* __restrict__ xpad, int n_src4, int n_tot4,
    const float* __restrict__ W1, u16* __restrict__ wt1,
    const float* __restrict__ W2, u16* __restrict__ wt2,
    const float* __restrict__ W3, u16* __restrict__ wt3,
    int DIN, int DH, int DOUT,
    int nb_cvt, int nb_w1, int nb_w2) {
  int b = blockIdx.x;
  if (b < nb_cvt) {                       // fp32 -> f16 convert + pad
    int i = b * 256 + threadIdx.x;
    if (i < n_tot4) {
      ushort4 o = {0, 0, 0, 0};
      if (i < n_src4) {
        float4 v = x[i];
        o.x = f2h(v.x); o.y = f2h(v.y); o.z = f2h(v.z); o.w = f2h(v.w);
      }
      xpad[i] = o;
    }
    return;
  }
  b -= nb_cvt;
  if (b < nb_w1) {                        // wt1[n*DIN+k] = W1[k*DH+n]
    int idx = b * 256 + threadIdx.x;
    if (idx < DIN * DH) {
      int n = idx / DIN, k = idx % DIN;
      wt1[idx] = f2h(W1[k * DH + n]);
    }
    return;
  }
  b -= nb_w1;
  if (b < nb_w2) {                        // wt2[n*DH+k] = W2[k*DH+n]
    int idx = b * 256 + threadIdx.x;
    if (idx < DH * DH) {
      int n = idx / DH, k = idx % DH;
      wt2[idx] = f2h(W2[k * DH + n]);
    }
    return;
  }
  b -= nb_w2;
  {                                       // wt3[n*DH+k] = W3[k*DOUT+n]
    int idx = b * 256 + threadIdx.x;
    if (idx < DH * DOUT) {
      int n = idx / DH, k = idx % DH;
      wt3[idx] = f2h(W3[k * DOUT + n]);
    }
  }
}

// ---------------- bucketed CSR build (coalesced; needs N <= 65536) -----
// bucket b = dst >> 8 (256 nodes). NCHUNK edge chunks.
#define NCHUNK 64

// A: per-chunk histogram over buckets. cnt[b*NCHUNK + c]
__global__ __launch_bounds__(256) void csr_hist(const void* __restrict__ ep,
                                                int* __restrict__ cnt, int E, int N) {
  __shared__ int h[256];
  h[threadIdx.x] = 0;
  __syncthreads();
  int is64 = wave_is64(ep);
  const int chunk = blockIdx.x;
  const int per = (E + NCHUNK - 1) / NCHUNK;
  const int e0 = chunk * per, e1 = min(e0 + per, E);
  for (int e = e0 + threadIdx.x; e < e1; e += 256) {
    int d = edge_at(ep, is64, (long long)E + e);
    d = min(max(d, 0), N - 1);
    atomicAdd(&h[d >> 8], 1);
  }
  __syncthreads();
  cnt[threadIdx.x * NCHUNK + chunk] = h[threadIdx.x];
}

// B: bucket totals -> exclusive bucket bases + per-(bucket,chunk) offsets.
__global__ __launch_bounds__(256) void csr_base(const int* __restrict__ cnt,
                                                int* __restrict__ bases,
                                                int* __restrict__ off,
                                                int nbuck, int E) {
  __shared__ int ws4[8];
  const int t = threadIdx.x, lane = t & 63, w = t >> 6;
  int tot = 0;
  if (t < nbuck)
#pragma unroll 8
    for (int c = 0; c < NCHUNK; ++c) tot += cnt[t * NCHUNK + c];
  // block-wide exclusive scan of tot over 256 threads
  int inc = tot;
#pragma unroll
  for (int o = 1; o < 64; o <<= 1) {
    int u = __shfl_up(inc, o, 64);
    if (lane >= o) inc += u;
  }
  if (lane == 63) ws4[w] = inc;
  __syncthreads();
  if (t == 0) {
    int run = 0;
#pragma unroll
    for (int k = 0; k < 4; ++k) { int v = ws4[k]; ws4[k + 4] = run; run += v; }
  }
  __syncthreads();
  const int base = ws4[w + 4] + inc - tot;   // exclusive prefix
  if (t < nbuck) {
    bases[t] = base;
    int run = base;
    for (int c = 0; c < NCHUNK; ++c) {
      off[t * NCHUNK + c] = run;
      run += cnt[t * NCHUNK + c];
    }
  }
  if (t == 0) bases[nbuck] = E;
}

// C: chunked scatter into bucket-contiguous tmp (packed dst16|src16)
__global__ __launch_bounds__(256) void csr_bucket(const void* __restrict__ ep,
                                                  const int* __restrict__ off,
                                                  unsigned* __restrict__ tmp,
                                                  int E, int N) {
  __shared__ int cur[256];
  const int chunk = blockIdx.x;
  const int nbuck = (N + 255) >> 8;
  if ((int)threadIdx.x < nbuck) cur[threadIdx.x] = off[threadIdx.x * NCHUNK + chunk];
  __syncthreads();
  int is64 = wave_is64(ep);
  const int per = (E + NCHUNK - 1) / NCHUNK;
  const int e0 = chunk * per, e1 = min(e0 + per, E);
  for (int e = e0 + threadIdx.x; e < e1; e += 256) {
    int s = edge_at(ep, is64, e);
    int d = edge_at(ep, is64, (long long)E + e);
    s = min(max(s, 0), N - 1);
    d = min(max(d, 0), N - 1);
    int pos = atomicAdd(&cur[d >> 8], 1);
    tmp[pos] = ((unsigned)d << 16) | (unsigned)s;
  }
}

// D: per-bucket: node histogram -> rp/dis + col scatter (L1-resident window)
__global__ __launch_bounds__(256) void csr_final(const unsigned* __restrict__ tmp,
                                                 const int* __restrict__ bases,
                                                 int* __restrict__ rp,
                                                 float* __restrict__ dis,
                                                 u16* __restrict__ col, int N, int E) {
  __shared__ int hcnt[256];
  __shared__ int curs[256];
  __shared__ int ws4[8];
  const int b = blockIdx.x;
  const int node0 = b * 256;
  const int t = threadIdx.x, lane = t & 63, w = t >> 6;
  hcnt[t] = 0;
  __syncthreads();
  const int k0 = bases[b];
  const int k1 = bases[b + 1];
  for (int k = k0 + t; k < k1; k += 256)
    atomicAdd(&hcnt[(int)(tmp[k] >> 16) - node0], 1);
  __syncthreads();
  const int v = hcnt[t];
  // block exclusive scan of v
  int inc = v;
#pragma unroll
  for (int o = 1; o < 64; o <<= 1) {
    int u = __shfl_up(inc, o, 64);
    if (lane >= o) inc += u;
  }
  if (lane == 63) ws4[w] = inc;
  __syncthreads();
  if (t == 0) {
    int run = 0;
#pragma unroll
    for (int k = 0; k < 4; ++k) { int vv = ws4[k]; ws4[k + 4] = run; run += vv; }
  }
  __syncthreads();
  const int excl = k0 + ws4[w + 4] + inc - v;
  if (node0 + t < N) {
    rp[node0 + t] = excl;
    dis[node0 + t] = rsqrtf((float)(v + 1));   // +1 = self loop
  }
  if (b == 0 && t == 0) rp[N] = E;
  curs[t] = excl;
  __syncthreads();
  for (int k = k0 + t; k < k1; k += 256) {
    unsigned e = tmp[k];
    int dl = (int)(e >> 16) - node0;
    int pos = atomicAdd(&curs[dl], 1);
    col[pos] = (u16)(e & 0xFFFFu);
  }
}

// ---------------- B-resident GEMM: C[M,Nt] = A[M,256] @ Bt[Nt,256]^T ----------
// Entire B panel (BN x 256 f16) staged in LDS once (fragment order), then a
// barrier-free K-loop: A fragments direct from global (16B row slices,
// prefetched), B fragments via conflict-free ds_read_b128.
template <int BN>
__global__ __launch_bounds__(256) void gemm_bres(const u16* __restrict__ A,
                                                 const u16* __restrict__ Bt,
                                                 u16* __restrict__ C, int Nt) {
  constexpr int K = 256;
  constexpr int NJ = BN / 16;            // 8 (BN=128) or 4 (BN=64)
  constexpr int CH = BN * K / 8;         // 16B chunks in panel
  __shared__ __align__(16) u16 Bs[BN * K];   // 64KB or 32KB

  const int tid = threadIdx.x, lane = tid & 63, w = tid >> 6;
  const int bm = blockIdx.x, bn = blockIdx.y;

  // stage B panel in fragment order: chunk c=(j*8+ks)*64+lane
#pragma unroll
  for (int i = 0; i < CH / 256; ++i) {
    int c = tid + i * 256;
    int ln = c & 63, t2 = c >> 6;
    int ks = t2 & 7, j = t2 >> 3;
    int row = j * 16 + (ln & 15);
    int kk = ks * 32 + (ln >> 4) * 8;
    async16(&Bs[(size_t)c * 8], Bt + (size_t)(bn * BN + row) * K + kk);
  }
  __syncthreads();                       // drains vmcnt -> panel visible

  const int r16 = lane & 15, quad = lane >> 4;
  const int m0 = w * 32;                 // 2 row-blocks per wave

  f32x4 acc[2][NJ];
  const f32x4 fzero = {0.f, 0.f, 0.f, 0.f};
#pragma unroll
  for (int i = 0; i < 2; ++i)
#pragma unroll
    for (int j = 0; j < NJ; ++j) acc[i][j] = fzero;

  const u16* Ap0 = A + (size_t)(bm * 128 + m0 + r16) * K + quad * 8;
  const u16* Ap1 = Ap0 + 16 * K;
  f16x8 a0 = *(const f16x8*)Ap0;
  f16x8 a1 = *(const f16x8*)Ap1;
#pragma unroll
  for (int ks = 0; ks < 8; ++ks) {
    f16x8 n0, n1;
    if (ks < 7) {                        // prefetch next A fragments
      n0 = *(const f16x8*)(Ap0 + (ks + 1) * 32);
      n1 = *(const f16x8*)(Ap1 + (ks + 1) * 32);
    }
#pragma unroll
    for (int j = 0; j < NJ; ++j) {
      f16x8 bf = *(const f16x8*)(&Bs[(size_t)((j * 8 + ks) * 64 + lane) * 8]);
      acc[0][j] = __builtin_amdgcn_mfma_f32_16x16x32_f16(a0, bf, acc[0][j], 0, 0, 0);
      acc[1][j] = __builtin_amdgcn_mfma_f32_16x16x32_f16(a1, bf, acc[1][j], 0, 0, 0);
    }
    if (ks < 7) { a0 = n0; a1 = n1; }
  }
#pragma unroll
  for (int i = 0; i < 2; ++i)
#pragma unroll
    for (int j = 0; j < NJ; ++j) {
      int gr = bm * 128 + m0 + i * 16 + quad * 4;   // C/D: col=lane&15, row=quad*4+r
      int gc = bn * BN + j * 16 + r16;
#pragma unroll
      for (int r = 0; r < 4; ++r)
        C[(size_t)(gr + r) * Nt + gc] = f2h(acc[i][j][r]);
    }
}

// ---------------- aggregation, d=256: half-wave = 1 edge, 4 loads deep,
// packed f16 accumulation, fp32 cross-half merge + epilogue ----
__global__ __launch_bounds__(256) void agg_d256(const u16* __restrict__ h,
                                                const int* __restrict__ rp,
                                                const u16* __restrict__ col,
                                                const float* __restrict__ dis,
                                                const float* __restrict__ bias,
                                                u16* __restrict__ out, int N) {
  const int wid = threadIdx.x >> 6, lane = threadIdx.x & 63;
  const int i = blockIdx.x * 4 + wid;
  if (i >= N) return;
  const int sub = lane >> 5;
  const int l32 = lane & 31;
  const int c8 = l32 * 8;
  const float di = dis[i];
  h2 acc[4];
  {
    uint4 sv = *(const uint4*)(h + (size_t)i * 256 + c8);
    const _Float16 w = (_Float16)(sub ? 0.f : di);
    const h2 ws = {w, w};
    acc[0] = __builtin_bit_cast(h2, sv.x) * ws;
    acc[1] = __builtin_bit_cast(h2, sv.y) * ws;
    acc[2] = __builtin_bit_cast(h2, sv.z) * ws;
    acc[3] = __builtin_bit_cast(h2, sv.w) * ws;
  }
  const int e1 = rp[i + 1];
  for (int base = rp[i]; base < e1; base += 64) {
    int me = base + lane;
    int s_l = 0; float d_l = 0.f;
    if (me < e1) { s_l = (int)col[me]; d_l = dis[s_l]; }
    const int cnt = min(64, e1 - base);
    const int cntR = (cnt + 7) & ~7;
    for (int t = 0; t < cntR; t += 8) {
      int sA = __shfl(s_l, t + sub, 64);      float dA = __shfl(d_l, t + sub, 64);
      int sB = __shfl(s_l, t + 2 + sub, 64);  float dB = __shfl(d_l, t + 2 + sub, 64);
      int sC = __shfl(s_l, t + 4 + sub, 64);  float dC = __shfl(d_l, t + 4 + sub, 64);
      int sD = __shfl(s_l, t + 6 + sub, 64);  float dD = __shfl(d_l, t + 6 + sub, 64);
      uint4 pA = *(const uint4*)(h + (size_t)sA * 256 + c8);
      uint4 pB = *(const uint4*)(h + (size_t)sB * 256 + c8);
      uint4 pC = *(const uint4*)(h + (size_t)sC * 256 + c8);
      uint4 pD = *(const uint4*)(h + (size_t)sD * 256 + c8);
      _Float16 hA = (_Float16)dA, hB = (_Float16)dB;
      _Float16 hC = (_Float16)dC, hD = (_Float16)dD;
      h2 wA = {hA, hA}, wB = {hB, hB}, wC = {hC, hC}, wD = {hD, hD};
      pkfma4(acc, wA, pA); pkfma4(acc, wB, pB);
      pkfma4(acc, wC, pC); pkfma4(acc, wD, pD);
    }
  }
  float a[8];
#pragma unroll
  for (int j = 0; j < 4; ++j) {
    a[2 * j] = (float)acc[j].x;
    a[2 * j + 1] = (float)acc[j].y;
  }
#pragma unroll
  for (int k = 0; k < 8; ++k) a[k] += __shfl_xor(a[k], 32, 64);
  if (sub == 0) {
    float4 b0 = *(const float4*)(bias + c8);
    float4 b1 = *(const float4*)(bias + c8 + 4);
    float r0 = fmaxf(di * a[0] + b0.x, 0.f), r1 = fmaxf(di * a[1] + b0.y, 0.f);
    float r2 = fmaxf(di * a[2] + b0.z, 0.f), r3 = fmaxf(di * a[3] + b0.w, 0.f);
    float r4 = fmaxf(di * a[4] + b1.x, 0.f), r5 = fmaxf(di * a[5] + b1.y, 0.f);
    float r6 = fmaxf(di * a[6] + b1.z, 0.f), r7 = fmaxf(di * a[7] + b1.w, 0.f);
    uint4 ov;
    ov.x = (unsigned)f2h(r0) | ((unsigned)f2h(r1) << 16);
    ov.y = (unsigned)f2h(r2) | ((unsigned)f2h(r3) << 16);
    ov.z = (unsigned)f2h(r4) | ((unsigned)f2h(r5) << 16);
    ov.w = (unsigned)f2h(r6) | ((unsigned)f2h(r7) << 16);
    *(uint4*)(out + (size_t)i * 256 + c8) = ov;
  }
}

// final layer: h f16 [N,64], out fp32 [N,64], fp32 accumulation
__global__ __launch_bounds__(256) void agg_d64(const u16* __restrict__ h,
                                               const int* __restrict__ rp,
                                               const u16* __restrict__ col,
                                               const float* __restrict__ dis,
                                               const float* __restrict__ bias,
                                               float* __restrict__ out, int N) {
  const int wid = threadIdx.x >> 6, lane = threadIdx.x & 63;
  const int i = blockIdx.x * 4 + wid;
  if (i >= N) return;
  const int grp = lane >> 3;
  const int l8 = lane & 7;
  const int c8 = l8 * 8;
  const float di = dis[i];
  float a[8];
  {
    uint4 sv = *(const uint4*)(h + (size_t)i * 64 + c8);
    const float w = (grp == 0) ? di : 0.f;
    a[0] = w * h2f((u16)sv.x); a[1] = w * h2f((u16)(sv.x >> 16));
    a[2] = w * h2f((u16)sv.y); a[3] = w * h2f((u16)(sv.y >> 16));
    a[4] = w * h2f((u16)sv.z); a[5] = w * h2f((u16)(sv.z >> 16));
    a[6] = w * h2f((u16)sv.w); a[7] = w * h2f((u16)(sv.w >> 16));
  }
  const int e1 = rp[i + 1];
  for (int base = rp[i]; base < e1; base += 64) {
    int me = base + lane;
    int s_l = 0; float d_l = 0.f;
    if (me < e1) { s_l = (int)col[me]; d_l = dis[s_l]; }
    const int cnt = min(64, e1 - base);
    const int cntR = (cnt + 15) & ~15;
    for (int t = 0; t < cntR; t += 16) {
      int sA = __shfl(s_l, t + grp, 64);       float dA = __shfl(d_l, t + grp, 64);
      int sB = __shfl(s_l, t + 8 + grp, 64);   float dB = __shfl(d_l, t + 8 + grp, 64);
      uint4 pA = *(const uint4*)(h + (size_t)sA * 64 + c8);
      uint4 pB = *(const uint4*)(h + (size_t)sB * 64 + c8);
      fma8(a, dA, pA); fma8(a, dB, pB);
    }
  }
#pragma unroll
  for (int k = 0; k < 8; ++k) a[k] += __shfl_xor(a[k], 8, 64);
#pragma unroll
  for (int k = 0; k < 8; ++k) a[k] += __shfl_xor(a[k], 16, 64);
#pragma unroll
  for (int k = 0; k < 8; ++k) a[k] += __shfl_xor(a[k], 32, 64);
  if (lane < 8) {
    float4 b0 = *(const float4*)(bias + c8);
    float4 b1 = *(const float4*)(bias + c8 + 4);
    float4 o0, o1;
    o0.x = di * a[0] + b0.x; o0.y = di * a[1] + b0.y;
    o0.z = di * a[2] + b0.z; o0.w = di * a[3] + b0.w;
    o1.x = di * a[4] + b1.x; o1.y = di * a[5] + b1.y;
    o1.z = di * a[6] + b1.z; o1.w = di * a[7] + b1.w;
    *(float4*)(out + (size_t)i * 64 + c8) = o0;
    *(float4*)(out + (size_t)i * 64 + c8 + 4) = o1;
  }
}

// ---------------- launch ----------------
extern "C" void kernel_launch(void* const* d_in, const int* in_sizes, int n_in,
                              void* d_out, int out_size, void* d_ws, size_t ws_size,
                              hipStream_t stream) {
  if (n_in < 8) return;
  const float* x = (const float*)d_in[0];
  const void* eptr = d_in[1];
  const float* W1 = (const float*)d_in[2];
  const float* b1 = (const float*)d_in[3];
  const float* W2 = (const float*)d_in[4];
  const float* b2 = (const float*)d_in[5];
  const float* W3 = (const float*)d_in[6];
  const float* b3 = (const float*)d_in[7];
  float* out = (float*)d_out;

  const int DIN = 256, DH = 256;
  const int N = in_sizes[0] / DIN;       // 50000
  const int E = in_sizes[1] / 2;         // 800000
  const int DOUT = in_sizes[6] / DH;     // 64
  const int MT = (N + 127) / 128;        // 391
  const int Mpad = MT * 128;
  const int nbuck = (N + 255) >> 8;      // 196

  auto rnd = [](size_t b) { return (b + 255) & ~(size_t)255; };
  size_t required = 0;
  required += rnd((size_t)Mpad * DH * 2) * 2;        // xpad + hbuf
  required += rnd((size_t)E * 2);                    // col (u16)
  required += rnd((size_t)E * 4);                    // tmp (packed pairs)
  required += rnd((size_t)(N + 1) * 4);              // rp
  required += rnd((size_t)N * 4);                    // dis
  required += rnd((size_t)DIN * DH * 2);             // wt1
  required += rnd((size_t)DH * DH * 2);              // wt2
  required += rnd((size_t)DH * DOUT * 2);            // wt3
  required += rnd((size_t)256 * NCHUNK * 4) * 2;     // cnt + off
  required += rnd((size_t)(nbuck + 1) * 4);          // bases
  if (ws_size < required || N > 65536 || nbuck > 256) {
    zero_f32<<<(out_size + 255) / 256, 256, 0, stream>>>(out, out_size);
    return;
  }

  char* ws = (char*)d_ws;
  size_t off0 = 0;
  auto alloc = [&](size_t bytes) {
    char* p = ws + off0;
    off0 = (off0 + bytes + 255) & ~(size_t)255;
    return p;
  };
  u16* xpad = (u16*)alloc((size_t)Mpad * DH * 2);
  u16* hbuf = (u16*)alloc((size_t)Mpad * DH * 2);
  u16* colb = (u16*)alloc((size_t)E * 2);
  unsigned* tmpb = (unsigned*)alloc((size_t)E * 4);
  int* rp = (int*)alloc((size_t)(N + 1) * 4);
  float* dis = (float*)alloc((size_t)N * 4);
  u16* wt1 = (u16*)alloc((size_t)DIN * DH * 2);
  u16* wt2 = (u16*)alloc((size_t)DH * DH * 2);
  u16* wt3 = (u16*)alloc((size_t)DH * DOUT * 2);
  int* cnt = (int*)alloc((size_t)256 * NCHUNK * 4);
  int* offs = (int*)alloc((size_t)256 * NCHUNK * 4);
  int* bases = (int*)alloc((size_t)(nbuck + 1) * 4);

  const int n_tot4 = Mpad * DH / 4;
  const int nb_cvt = (n_tot4 + 255) / 256;
  const int nb_w1 = (DIN * DH + 255) / 256;
  const int nb_w2 = (DH * DH + 255) / 256;
  const int nb_w3 = (DH * DOUT + 255) / 256;
  prep_fused<<<nb_cvt + nb_w1 + nb_w2 + nb_w3, 256, 0, stream>>>(
      (const float4*)x, (ushort4*)xpad, N * DH / 4, n_tot4,
      W1, wt1, W2, wt2, W3, wt3, DIN, DH, DOUT, nb_cvt, nb_w1, nb_w2);

  // bucketed CSR build (also produces rp + dis)
  csr_hist<<<NCHUNK, 256, 0, stream>>>(eptr, cnt, E, N);
  csr_base<<<1, 256, 0, stream>>>(cnt, bases, offs, nbuck, E);
  csr_bucket<<<NCHUNK, 256, 0, stream>>>(eptr, offs, tmpb, E, N);
  csr_final<<<nbuck, 256, 0, stream>>>(tmpb, bases, rp, dis, colb, N, E);

  // layer 1
  gemm_bres<128><<<dim3(MT, DH / 128), 256, 0, stream>>>(xpad, wt1, hbuf, DH);
  agg_d256<<<(N + 3) / 4, 256, 0, stream>>>(hbuf, rp, colb, dis, b1, xpad, N);
  // layer 2
  gemm_bres<128><<<dim3(MT, DH / 128), 256, 0, stream>>>(xpad, wt2, hbuf, DH);
  agg_d256<<<(N + 3) / 4, 256, 0, stream>>>(hbuf, rp, colb, dis, b2, xpad, N);
  // layer 3
  gemm_bres<64><<<dim3(MT, DOUT / 64), 256, 0, stream>>>(xpad, wt3, hbuf, DOUT);
  agg_d64<<<(N + 3) / 4, 256, 0, stream>>>(hbuf, rp, colb, dis, b3, out, N);
}